// Round 8
// baseline (508.761 us; speedup 1.0000x reference)
//
#include <hip/hip_runtime.h>
#include <cstdint>
#include <cstddef>

// ---------------------------------------------------------------------------
// feature_matching: corr(P=20, C=64) -> 4x (depthwise 3^3 + pointwise) blocks
//
// R8: de-fatten. R7's W8=8 paths blew VGPR to 116 and occupancy to 14%.
//  - All fused blocks use 4-wide tasks (acc[DT][4][4], VGPR ~60).
//  - b1 keeps HT=8 (FETCH 189->99 MB in R7) but at W=4; others HT=4.
//  - corr v3 (barrier-free, A-frags reused over 4 di) retained.
//  - CINP odd dword stride (22/42), no extra swizzle.
//  - fb1..fb4 are distinct __global__ names -> per-stage profile visibility.
//
// ws layout (peak 157,286,400 B):
//   [0,        78.6MB): corrO (f16)        -> later b2o (f16, 19.7MB)
//   [78.6MB,  157.3MB): rgbT+depT (f16)    -> later b1o (f16, 78.6MB)
//                                          -> later b3o (f16, 19.7MB)
// ---------------------------------------------------------------------------

typedef unsigned short u16;
typedef _Float16 f16_t;
typedef __attribute__((ext_vector_type(2))) _Float16 half2_t;
typedef __attribute__((ext_vector_type(8))) _Float16 half8_t;
typedef __attribute__((ext_vector_type(4))) float f32x4;

static __device__ inline u16 f2h(float f) {
    union { f16_t h; u16 u; } v; v.h = (f16_t)f; return v.u;
}
static __device__ inline half2_t H2(uint32_t u) {
    union { uint32_t u; half2_t h; } v; v.u = u; return v.h;
}

#if __has_builtin(__builtin_amdgcn_fdot2)
static __device__ inline float FDOT2(half2_t a, half2_t b, float c) {
    return __builtin_amdgcn_fdot2(a, b, c, false);
}
#else
static __device__ inline float FDOT2(half2_t a, half2_t b, float c) {
    return fmaf((float)a.x, (float)b.x, fmaf((float)a.y, (float)b.y, c));
}
#endif

#if __has_builtin(__builtin_amdgcn_alignbit)
static __device__ inline uint32_t mkp(uint32_t lo, uint32_t hi) {
    return __builtin_amdgcn_alignbit(hi, lo, 16);   // (lo.hi16, hi.lo16)
}
#else
static __device__ inline uint32_t mkp(uint32_t lo, uint32_t hi) {
    return (lo >> 16) | (hi << 16);
}
#endif

static __device__ inline uint32_t ldu(const u16* p) { return *(const uint32_t*)p; }

// ---------------------------------------------------------------------------
// Prepass: (b,c,h,w) fp32 -> (b,h,w,c) f16, LDS tile transpose per (b,h).
// ---------------------------------------------------------------------------
__global__ __launch_bounds__(256) void transpose_f16(
        const float* __restrict__ rgb, const float* __restrict__ dep,
        u16* __restrict__ rgbT, u16* __restrict__ depT) {
    const int bh = blockIdx.x;
    const float* src = blockIdx.y ? dep : rgb;
    u16* dst = blockIdx.y ? depT : rgbT;
    const int tid = threadIdx.x;
    const int b = bh >> 6, h = bh & 63;

    __shared__ u16 S[64 * 194];

    const float* srcb = src + (size_t)b * 786432 + (size_t)h * 192;
#pragma unroll
    for (int it = 0; it < 12; ++it) {
        const int idx = it * 256 + tid;      // 3072 = 64c x 48 float4
        const int c = idx / 48, w4 = idx - c * 48;
        const float4 v = *(const float4*)(srcb + (size_t)c * 12288 + 4 * w4);
        u16* sp = &S[c * 194 + 4 * w4];
        sp[0] = f2h(v.x); sp[1] = f2h(v.y); sp[2] = f2h(v.z); sp[3] = f2h(v.w);
    }
    __syncthreads();
    u16* dstb = dst + (size_t)bh * 192 * 64;
#pragma unroll
    for (int it = 0; it < 12; ++it) {
        const int idx = it * 256 + tid;      // 3072 = 192w x 16 c4
        const int w = idx >> 4, c4 = idx & 15;
        ushort4 o;
        o.x = S[(4 * c4 + 0) * 194 + w];
        o.y = S[(4 * c4 + 1) * 194 + w];
        o.z = S[(4 * c4 + 2) * 194 + w];
        o.w = S[(4 * c4 + 3) * 194 + w];
        *(ushort4*)(dstb + (size_t)w * 64 + 4 * c4) = o;
    }
}

// ---------------------------------------------------------------------------
// corr v3. Grid (dig=5, h=64, b=8), 256 threads (4 waves, no barriers).
// Wave owns 48 w; A-frags (rgb row) loaded once, reused over 4 di.
// Per di: banded Z via f16 MFMA, scatter to the wave's PRIVATE Dall slice
// in (w,dj) coords, wave-local readout (no cross-wave data).
// ---------------------------------------------------------------------------
__global__ __launch_bounds__(256) void corr_mfma(
        const u16* __restrict__ rgbT, const u16* __restrict__ depT,
        u16* __restrict__ out) {
    const int dig = blockIdx.x, h = blockIdx.y, b = blockIdx.z;
    const int tid = threadIdx.x;
    const int lane = tid & 63, wave = tid >> 6;
    const int n = lane & 15, q = lane >> 4;

    __shared__ float Dall[4080];         // addr = w*21 + (w>>2) + dj

    const u16* Abase = rgbT + (size_t)(b * 64 + h) * 12288;
    half8_t a0[3], a1[3];
#pragma unroll
    for (int t = 0; t < 3; ++t) {
        const int w0 = wave * 48 + t * 16;
        const half8_t* Ap = (const half8_t*)(Abase + (size_t)(w0 + n) * 64 + q * 8);
        a0[t] = Ap[0];                   // c = q*8 .. q*8+7
        a1[t] = Ap[4];                   // c += 32
    }

#pragma unroll
    for (int i = 0; i < 4; ++i) {
        const int di = dig * 4 + i;
        const int hd = h + di - 10;
        u16* outb = out + ((size_t)((b * 20 + di) * 20) * 64 + h) * 192;

        if (hd < 0 || hd >= 64) {        // depth row fully in zero-pad
#pragma unroll
            for (int it = 0; it < 4; ++it) {
                const int item = it * 64 + lane;
                if (item < 240) {
                    const int dj = item / 12;
                    const int w4 = wave * 12 + (item - dj * 12);
                    *(ushort4*)(outb + (size_t)dj * 12288 + 4 * w4) =
                        make_ushort4(0, 0, 0, 0);
                }
            }
            continue;
        }

        const u16* Bbase = depT + (size_t)(b * 64 + hd) * 12288;
#pragma unroll
        for (int t = 0; t < 3; ++t) {
            const int w0 = wave * 48 + t * 16;
            f32x4 acc[3];
#pragma unroll
            for (int ut = 0; ut < 3; ++ut) {
                acc[ut].x = 0.f; acc[ut].y = 0.f; acc[ut].z = 0.f; acc[ut].w = 0.f;
            }
#pragma unroll
            for (int ut = 0; ut < 3; ++ut) {
                const int u0 = w0 + (ut - 1) * 16;
                if (u0 >= 0 && u0 <= 176) {  // wave-uniform; OOB tile stays 0
                    const half8_t* Bp = (const half8_t*)(Bbase + (size_t)(u0 + n) * 64 + q * 8);
                    acc[ut] = __builtin_amdgcn_mfma_f32_16x16x32_f16(a0[t], Bp[0], acc[ut], 0, 0, 0);
                    acc[ut] = __builtin_amdgcn_mfma_f32_16x16x32_f16(a1[t], Bp[4], acc[ut], 0, 0, 0);
                }
            }
#pragma unroll
            for (int ut = 0; ut < 3; ++ut) {
#pragma unroll
                for (int r = 0; r < 4; ++r) {
                    const int dj = 16 * ut + n - 4 * q - r - 6;
                    const int w = w0 + 4 * q + r;
                    if (dj >= 0 && dj < 20)
                        Dall[w * 21 + (w >> 2) + dj] = acc[ut][r];
                }
            }
        }
        // wave-local readout (writes above are by this wave only)
#pragma unroll
        for (int it = 0; it < 4; ++it) {
            const int item = it * 64 + lane;
            if (item < 240) {
                const int dj = item / 12;
                const int w4 = wave * 12 + (item - dj * 12);
                const int base = 85 * w4 + dj;   // (4*w4+j)*21 + w4 + dj
                ushort4 o;
                o.x = f2h(Dall[base]);
                o.y = f2h(Dall[base + 21]);
                o.z = f2h(Dall[base + 42]);
                o.w = f2h(Dall[base + 63]);
                *(ushort4*)(outb + (size_t)dj * 12288 + 4 * w4) = o;
            }
        }
    }
}

// ---------------------------------------------------------------------------
// Fused block v7 (device body). 4-wide tasks only. Tile DT d x HT h x 48 w.
// Phase 1 task = (ci, wg, hh2): 4 w x 4 h x DT d outputs via fdot2 (fp32
// accum), merged plane loop; interior blocks take guard-free unrolled path.
// dw out (bias+leaky, f16) -> LDS sT[pos][ci], stride CINP odd-dword.
// Phase 2 = f16 MFMA (M=16 w, N=16 co, K=32 ci).
// ---------------------------------------------------------------------------
template<int CIN, int COUT, int S, int DT, int HT, int DIN, int HIN, int WIN,
         int DO, int HO, int WO, typename TOUT>
static __device__ __forceinline__ void fused_impl(
        const u16* __restrict__ x,
        const float* __restrict__ dw_w, const float* __restrict__ dw_b,
        const float* __restrict__ pw_w, const float* __restrict__ pw_b,
        TOUT* __restrict__ y) {
    static_assert(WO % 48 == 0 && HO % HT == 0 && (HT == 4 || HT == 8), "tile");
    constexpr int CINP = (CIN == 20) ? 22 : 42;    // odd dword stride
    constexpr int HH = HT / 4;
    constexpr int SUB = 12 * HH;                   // tasks per ci (4-wide)
    constexpr int NTASK = CIN * SUB;
    constexpr int WT = WO / 48;
    constexpr int NP = S * (DT - 1) + 3;

    const int wt = blockIdx.x % WT;
    const int ht = blockIdx.x / WT;
    const int d0 = blockIdx.y * DT;
    const int b  = blockIdx.z;
    const int tid = threadIdx.x;
    const int h0 = ht * HT;
    const int wbase = wt * 48;

    __shared__ float sDW[CIN * 27];
    __shared__ float sDB[CIN];
    __shared__ u16   sT[DT * HT * 48 * CINP + 16];

    for (int i = tid; i < CIN * 27; i += 256) sDW[i] = dw_w[i];
    for (int i = tid; i < CIN; i += 256) sDB[i] = dw_b[i];
    __syncthreads();

    // ---------------- phase 1: depthwise via fdot2 ----------------
    for (int idx = tid; idx < NTASK; idx += 256) {
        const int ci = idx / SUB;
        const int rem = idx - ci * SUB;
        const int wg = rem / HH;
        const int hh2 = rem - wg * HH;
        const int w0g = wbase + wg * 4;
        const int h0t = h0 + hh2 * 4;

        half2_t KA[9], KB[9];
#pragma unroll
        for (int t = 0; t < 9; ++t) {
            const int kd = t / 3, kh = t - 3 * kd;
            const float k0 = sDW[ci * 27 + kd * 9 + kh * 3 + 0];
            const float k1 = sDW[ci * 27 + kd * 9 + kh * 3 + 1];
            const float k2 = sDW[ci * 27 + kd * 9 + kh * 3 + 2];
            half2_t a; a.x = (f16_t)k0; a.y = (f16_t)k1; KA[t] = a;
            half2_t bb;
            if constexpr (S == 1) { bb.x = (f16_t)k2; bb.y = (f16_t)0.f; }
            else                  { bb.x = (f16_t)0.f; bb.y = (f16_t)k2; }
            KB[t] = bb;
        }

        float acc[DT][4][4];
#pragma unroll
        for (int dl = 0; dl < DT; ++dl)
#pragma unroll
            for (int a = 0; a < 4; ++a)
#pragma unroll
                for (int c = 0; c < 4; ++c) acc[dl][a][c] = 0.f;

        const u16* plane0 = x + (size_t)(b * CIN + ci) * DIN * HIN * WIN;

        auto row_body = [&](int p, int r, const u16* pl) {
            const int hin = h0t * S - 1 + r;
            const u16* rowp = pl + (size_t)hin * WIN + (size_t)w0g * S;
            uint32_t PA[4], PB[4];
            if constexpr (S == 1) {
                const uint32_t D0 = (w0g > 0) ? ldu(rowp - 2) : 0u;
                const uint32_t D1 = ldu(rowp);
                const uint32_t D2 = ldu(rowp + 2);
                const uint32_t D3 = (w0g + 4 < WIN) ? ldu(rowp + 4) : 0u;
                const uint32_t m01 = mkp(D0, D1);  // (x-1,x0)
                const uint32_t m12 = mkp(D1, D2);  // (x1,x2)
                const uint32_t m23 = mkp(D2, D3);  // (x3,x4)
                PA[0] = m01; PA[1] = D1; PA[2] = m12; PA[3] = D2;
                PB[0] = m12; PB[1] = D2; PB[2] = m23; PB[3] = D3;
            } else {
                const uint32_t E0 = (w0g > 0) ? ldu(rowp - 2) : 0u;
                const uint32_t E1 = ldu(rowp);
                const uint32_t E2 = ldu(rowp + 2);
                const uint32_t E3 = ldu(rowp + 4);
                const uint32_t E4 = ldu(rowp + 6);
                PA[0] = mkp(E0, E1); PA[1] = mkp(E1, E2);
                PA[2] = mkp(E2, E3); PA[3] = mkp(E3, E4);
                PB[0] = E1; PB[1] = E2; PB[2] = E3; PB[3] = E4;
            }
#pragma unroll
            for (int dl = 0; dl < DT; ++dl) {
                const int kd = p - S * dl;             // folds after unroll
                if (kd < 0 || kd > 2) continue;
#pragma unroll
                for (int hh = 0; hh < 4; ++hh) {
                    const int kh = r - S * hh;         // folds after unroll
                    if (kh < 0 || kh > 2) continue;
                    const int t = kd * 3 + kh;
#pragma unroll
                    for (int k = 0; k < 4; ++k)
                        acc[dl][hh][k] = FDOT2(H2(PB[k]), KB[t],
                                         FDOT2(H2(PA[k]), KA[t],
                                               acc[dl][hh][k]));
                }
            }
        };

        const bool dInt = (S * d0 - 1 >= 0) && (S * d0 - 1 + NP - 1 < DIN);
        const bool hInt = (h0t * S - 1 >= 0) && (h0t * S - 1 + 3 * S + 2 < HIN);
        if (dInt && hInt) {
#pragma unroll
            for (int p = 0; p < NP; ++p) {
                const u16* pl = plane0 + (size_t)(S * d0 - 1 + p) * HIN * WIN;
#pragma unroll
                for (int r = 0; r < 3 * S + 3; ++r) row_body(p, r, pl);
            }
        } else {
#pragma unroll
            for (int p = 0; p < NP; ++p) {
                const int din = S * d0 - 1 + p;
                if (din < 0 || din >= DIN) continue;
                const u16* pl = plane0 + (size_t)din * HIN * WIN;
#pragma unroll
                for (int r = 0; r < 3 * S + 3; ++r) {
                    const int hin = h0t * S - 1 + r;
                    if (hin < 0 || hin >= HIN) continue;
                    row_body(p, r, pl);
                }
            }
        }

        const float bia = sDB[ci];
#pragma unroll
        for (int dl = 0; dl < DT; ++dl) {
#pragma unroll
            for (int hh = 0; hh < 4; ++hh) {
                const int h = hh2 * 4 + hh;
#pragma unroll
                for (int k = 0; k < 4; ++k) {
                    const float t = acc[dl][hh][k] + bia;
                    sT[((dl * HT + h) * 48 + wg * 4 + k) * CINP + ci] =
                        f2h(fmaxf(t, 0.1f * t));
                }
            }
        }
    }
    __syncthreads();

    // ---------------- phase 2: pointwise via f16 MFMA ----------------
    constexpr int NT = (COUT + 15) / 16;   // co tiles
    constexpr int KH = (CIN + 31) / 32;    // K=32 chunks
    constexpr int MTW = DT * HT * 3 / 4;   // M-tiles per wave
    const int lane = tid & 63, wave = tid >> 6;
    const int m15 = lane & 15, q = lane >> 4;

    half8_t bf[NT][KH];
    float   pb[NT];
#pragma unroll
    for (int nt = 0; nt < NT; ++nt) {
        const int co = nt * 16 + m15;
        pb[nt] = (co < COUT) ? pw_b[co] : 0.f;
#pragma unroll
        for (int kh = 0; kh < KH; ++kh) {
            union { half8_t v; f16_t e[8]; } u;
#pragma unroll
            for (int j = 0; j < 8; ++j) {
                const int ci = kh * 32 + q * 8 + j;
                u.e[j] = (co < COUT && ci < CIN)
                         ? (f16_t)pw_w[co * CIN + ci] : (f16_t)0.f;
            }
            bf[nt][kh] = u.v;
        }
    }

    const size_t planeSz = (size_t)DO * HO * WO;
    for (int mt = wave * MTW; mt < (wave + 1) * MTW; ++mt) {
        const int dl  = mt / (HT * 3);
        const int rem = mt - dl * (HT * 3);
        const int hh  = rem / 3;
        const int w0  = (rem - hh * 3) * 16;
        if (d0 + dl >= DO) continue;           // tail guard

        const int pos0 = (dl * HT + hh) * 48 + w0 + m15;
        const u16* ap = &sT[(size_t)pos0 * CINP];
        union { uint32_t u[4]; half8_t v; } af[KH];
#pragma unroll
        for (int kh = 0; kh < KH; ++kh) {
            const int ci0 = kh * 32 + q * 8;
            af[kh].u[0] = (ci0     < CIN) ? ldu(ap + ci0)     : 0u;
            af[kh].u[1] = (ci0 + 2 < CIN) ? ldu(ap + ci0 + 2) : 0u;
            af[kh].u[2] = (ci0 + 4 < CIN) ? ldu(ap + ci0 + 4) : 0u;
            af[kh].u[3] = (ci0 + 6 < CIN) ? ldu(ap + ci0 + 6) : 0u;
        }
#pragma unroll
        for (int nt = 0; nt < NT; ++nt) {
            f32x4 acc;
            acc.x = 0.f; acc.y = 0.f; acc.z = 0.f; acc.w = 0.f;
#pragma unroll
            for (int kh = 0; kh < KH; ++kh)
                acc = __builtin_amdgcn_mfma_f32_16x16x32_f16(
                          af[kh].v, bf[nt][kh], acc, 0, 0, 0);
            const int co = nt * 16 + m15;
            if (co < COUT) {
                const float bias = pb[nt];
                TOUT* yp = y + (size_t)b * COUT * planeSz + (size_t)co * planeSz
                             + (size_t)(d0 + dl) * HO * WO
                             + (size_t)(h0 + hh) * WO + wbase + w0 + q * 4;
                float s0 = acc.x + bias, s1 = acc.y + bias;
                float s2 = acc.z + bias, s3 = acc.w + bias;
                s0 = fmaxf(s0, 0.1f * s0); s1 = fmaxf(s1, 0.1f * s1);
                s2 = fmaxf(s2, 0.1f * s2); s3 = fmaxf(s3, 0.1f * s3);
                if constexpr (sizeof(TOUT) == 4) {
                    float4 o; o.x = s0; o.y = s1; o.z = s2; o.w = s3;
                    *(float4*)yp = o;
                } else {
                    ushort4 o;
                    o.x = f2h(s0); o.y = f2h(s1); o.z = f2h(s2); o.w = f2h(s3);
                    *(ushort4*)yp = o;
                }
            }
        }
    }
}

// Named wrappers -> per-stage visibility in rocprof.
__global__ __launch_bounds__(256) void fb1_dwpw(
        const u16* __restrict__ x, const float* __restrict__ dww,
        const float* __restrict__ dwb, const float* __restrict__ pww,
        const float* __restrict__ pwb, u16* __restrict__ y) {
    fused_impl<20, 20, 1, 2, 8, 20, 64, 192, 20, 64, 192, u16>(x, dww, dwb, pww, pwb, y);
}
__global__ __launch_bounds__(256) void fb2_dwpw(
        const u16* __restrict__ x, const float* __restrict__ dww,
        const float* __restrict__ dwb, const float* __restrict__ pww,
        const float* __restrict__ pwb, u16* __restrict__ y) {
    fused_impl<20, 40, 2, 2, 4, 20, 64, 192, 10, 32, 96, u16>(x, dww, dwb, pww, pwb, y);
}
__global__ __launch_bounds__(256) void fb3_dwpw(
        const u16* __restrict__ x, const float* __restrict__ dww,
        const float* __restrict__ dwb, const float* __restrict__ pww,
        const float* __restrict__ pwb, u16* __restrict__ y) {
    fused_impl<40, 40, 1, 2, 4, 10, 32, 96, 10, 32, 96, u16>(x, dww, dwb, pww, pwb, y);
}
__global__ __launch_bounds__(256) void fb4_dwpw(
        const u16* __restrict__ x, const float* __restrict__ dww,
        const float* __restrict__ dwb, const float* __restrict__ pww,
        const float* __restrict__ pwb, float* __restrict__ y) {
    fused_impl<40, 80, 2, 1, 4, 10, 32, 96, 5, 16, 48, float>(x, dww, dwb, pww, pwb, y);
}

// ---------------------------------------------------------------------------
extern "C" void kernel_launch(void* const* d_in, const int* in_sizes, int n_in,
                              void* d_out, int out_size, void* d_ws, size_t ws_size,
                              hipStream_t stream) {
    const float* rgb  = (const float*)d_in[0];
    const float* dep  = (const float*)d_in[1];
    const float* dw1w = (const float*)d_in[2];
    const float* dw1b = (const float*)d_in[3];
    const float* pw1w = (const float*)d_in[4];
    const float* pw1b = (const float*)d_in[5];
    const float* dw2w = (const float*)d_in[6];
    const float* dw2b = (const float*)d_in[7];
    const float* pw2w = (const float*)d_in[8];
    const float* pw2b = (const float*)d_in[9];
    const float* dw3w = (const float*)d_in[10];
    const float* dw3b = (const float*)d_in[11];
    const float* pw3w = (const float*)d_in[12];
    const float* pw3b = (const float*)d_in[13];
    const float* dw4w = (const float*)d_in[14];
    const float* dw4b = (const float*)d_in[15];
    const float* pw4w = (const float*)d_in[16];
    const float* pw4b = (const float*)d_in[17];

    const size_t HALF = 78643200;
    u16* corrO = (u16*)d_ws;
    u16* rgbT  = (u16*)((char*)d_ws + HALF);
    u16* depT  = (u16*)((char*)d_ws + HALF + 12582912);
    u16* b1o   = (u16*)((char*)d_ws + HALF);   // rgbT/depT dead by then
    u16* b2o   = (u16*)d_ws;                   // corrO dead by then
    u16* b3o   = (u16*)((char*)d_ws + HALF);   // b1o dead by then
    float* outp = (float*)d_out;

    transpose_f16<<<dim3(512, 2), 256, 0, stream>>>(rgb, dep, rgbT, depT);

    corr_mfma<<<dim3(5, 64, 8), 256, 0, stream>>>(rgbT, depT, corrO);

    fb1_dwpw<<<dim3(32, 10, 8), 256, 0, stream>>>(corrO, dw1w, dw1b, pw1w, pw1b, b1o);
    fb2_dwpw<<<dim3(16, 5, 8), 256, 0, stream>>>(b1o, dw2w, dw2b, pw2w, pw2b, b2o);
    fb3_dwpw<<<dim3(16, 5, 8), 256, 0, stream>>>(b2o, dw3w, dw3b, pw3w, pw3b, b3o);
    fb4_dwpw<<<dim3(4, 5, 8), 256, 0, stream>>>(b3o, dw4w, dw4b, pw4w, pw4b, outp);
}

// Round 9
// 420.579 us; speedup vs baseline: 1.2097x; 1.2097x over previous
//
#include <hip/hip_runtime.h>
#include <cstdint>
#include <cstddef>

// ---------------------------------------------------------------------------
// feature_matching: corr(P=20, C=64) -> 4x (depthwise 3^3 + pointwise) blocks
//
// R9: occupancy-first revert. Empirical rule from R5..R8: these conv kernels
// are latency-bound; LDS <= ~21KB and VGPR <= ~48 (3+ blocks/CU) beats any
// per-thread efficiency or halo-fetch win that costs occupancy.
//  - single guarded plane/row loop (no interior dual path -> VGPR ~44)
//  - HT=4 everywhere; fb3 DT=1 (its DT=2 sT was a hidden 37KB cliff)
//  - odd CINP (22/42), corr v3 (barrier-free), f16 fdot2 + MFMA pointwise
//  - named kernels fb1..fb4 for per-stage profile attribution
//
// ws layout (peak 157,286,400 B):
//   [0,        78.6MB): corrO (f16)        -> later b2o (f16, 19.7MB)
//   [78.6MB,  157.3MB): rgbT+depT (f16)    -> later b1o (f16, 78.6MB)
//                                          -> later b3o (f16, 19.7MB)
// ---------------------------------------------------------------------------

typedef unsigned short u16;
typedef _Float16 f16_t;
typedef __attribute__((ext_vector_type(2))) _Float16 half2_t;
typedef __attribute__((ext_vector_type(8))) _Float16 half8_t;
typedef __attribute__((ext_vector_type(4))) float f32x4;

static __device__ inline u16 f2h(float f) {
    union { f16_t h; u16 u; } v; v.h = (f16_t)f; return v.u;
}
static __device__ inline half2_t H2(uint32_t u) {
    union { uint32_t u; half2_t h; } v; v.u = u; return v.h;
}

#if __has_builtin(__builtin_amdgcn_fdot2)
static __device__ inline float FDOT2(half2_t a, half2_t b, float c) {
    return __builtin_amdgcn_fdot2(a, b, c, false);
}
#else
static __device__ inline float FDOT2(half2_t a, half2_t b, float c) {
    return fmaf((float)a.x, (float)b.x, fmaf((float)a.y, (float)b.y, c));
}
#endif

#if __has_builtin(__builtin_amdgcn_alignbit)
static __device__ inline uint32_t mkp(uint32_t lo, uint32_t hi) {
    return __builtin_amdgcn_alignbit(hi, lo, 16);   // (lo.hi16, hi.lo16)
}
#else
static __device__ inline uint32_t mkp(uint32_t lo, uint32_t hi) {
    return (lo >> 16) | (hi << 16);
}
#endif

static __device__ inline uint32_t ldu(const u16* p) { return *(const uint32_t*)p; }

// ---------------------------------------------------------------------------
// Prepass: (b,c,h,w) fp32 -> (b,h,w,c) f16, LDS tile transpose per (b,h).
// ---------------------------------------------------------------------------
__global__ __launch_bounds__(256) void transpose_f16(
        const float* __restrict__ rgb, const float* __restrict__ dep,
        u16* __restrict__ rgbT, u16* __restrict__ depT) {
    const int bh = blockIdx.x;
    const float* src = blockIdx.y ? dep : rgb;
    u16* dst = blockIdx.y ? depT : rgbT;
    const int tid = threadIdx.x;
    const int b = bh >> 6, h = bh & 63;

    __shared__ u16 S[64 * 194];

    const float* srcb = src + (size_t)b * 786432 + (size_t)h * 192;
#pragma unroll
    for (int it = 0; it < 12; ++it) {
        const int idx = it * 256 + tid;      // 3072 = 64c x 48 float4
        const int c = idx / 48, w4 = idx - c * 48;
        const float4 v = *(const float4*)(srcb + (size_t)c * 12288 + 4 * w4);
        u16* sp = &S[c * 194 + 4 * w4];
        sp[0] = f2h(v.x); sp[1] = f2h(v.y); sp[2] = f2h(v.z); sp[3] = f2h(v.w);
    }
    __syncthreads();
    u16* dstb = dst + (size_t)bh * 192 * 64;
#pragma unroll
    for (int it = 0; it < 12; ++it) {
        const int idx = it * 256 + tid;      // 3072 = 192w x 16 c4
        const int w = idx >> 4, c4 = idx & 15;
        ushort4 o;
        o.x = S[(4 * c4 + 0) * 194 + w];
        o.y = S[(4 * c4 + 1) * 194 + w];
        o.z = S[(4 * c4 + 2) * 194 + w];
        o.w = S[(4 * c4 + 3) * 194 + w];
        *(ushort4*)(dstb + (size_t)w * 64 + 4 * c4) = o;
    }
}

// ---------------------------------------------------------------------------
// corr v3. Grid (dig=5, h=64, b=8), 256 threads (4 waves, no barriers).
// Wave owns 48 w; A-frags (rgb row) loaded once, reused over 4 di.
// ---------------------------------------------------------------------------
__global__ __launch_bounds__(256) void corr_mfma(
        const u16* __restrict__ rgbT, const u16* __restrict__ depT,
        u16* __restrict__ out) {
    const int dig = blockIdx.x, h = blockIdx.y, b = blockIdx.z;
    const int tid = threadIdx.x;
    const int lane = tid & 63, wave = tid >> 6;
    const int n = lane & 15, q = lane >> 4;

    __shared__ float Dall[4080];         // addr = w*21 + (w>>2) + dj

    const u16* Abase = rgbT + (size_t)(b * 64 + h) * 12288;
    half8_t a0[3], a1[3];
#pragma unroll
    for (int t = 0; t < 3; ++t) {
        const int w0 = wave * 48 + t * 16;
        const half8_t* Ap = (const half8_t*)(Abase + (size_t)(w0 + n) * 64 + q * 8);
        a0[t] = Ap[0];                   // c = q*8 .. q*8+7
        a1[t] = Ap[4];                   // c += 32
    }

#pragma unroll
    for (int i = 0; i < 4; ++i) {
        const int di = dig * 4 + i;
        const int hd = h + di - 10;
        u16* outb = out + ((size_t)((b * 20 + di) * 20) * 64 + h) * 192;

        if (hd < 0 || hd >= 64) {        // depth row fully in zero-pad
#pragma unroll
            for (int it = 0; it < 4; ++it) {
                const int item = it * 64 + lane;
                if (item < 240) {
                    const int dj = item / 12;
                    const int w4 = wave * 12 + (item - dj * 12);
                    *(ushort4*)(outb + (size_t)dj * 12288 + 4 * w4) =
                        make_ushort4(0, 0, 0, 0);
                }
            }
            continue;
        }

        const u16* Bbase = depT + (size_t)(b * 64 + hd) * 12288;
#pragma unroll
        for (int t = 0; t < 3; ++t) {
            const int w0 = wave * 48 + t * 16;
            f32x4 acc[3];
#pragma unroll
            for (int ut = 0; ut < 3; ++ut) {
                acc[ut].x = 0.f; acc[ut].y = 0.f; acc[ut].z = 0.f; acc[ut].w = 0.f;
            }
#pragma unroll
            for (int ut = 0; ut < 3; ++ut) {
                const int u0 = w0 + (ut - 1) * 16;
                if (u0 >= 0 && u0 <= 176) {  // wave-uniform; OOB tile stays 0
                    const half8_t* Bp = (const half8_t*)(Bbase + (size_t)(u0 + n) * 64 + q * 8);
                    acc[ut] = __builtin_amdgcn_mfma_f32_16x16x32_f16(a0[t], Bp[0], acc[ut], 0, 0, 0);
                    acc[ut] = __builtin_amdgcn_mfma_f32_16x16x32_f16(a1[t], Bp[4], acc[ut], 0, 0, 0);
                }
            }
#pragma unroll
            for (int ut = 0; ut < 3; ++ut) {
#pragma unroll
                for (int r = 0; r < 4; ++r) {
                    const int dj = 16 * ut + n - 4 * q - r - 6;
                    const int w = w0 + 4 * q + r;
                    if (dj >= 0 && dj < 20)
                        Dall[w * 21 + (w >> 2) + dj] = acc[ut][r];
                }
            }
        }
        // wave-local readout (writes above are by this wave only)
#pragma unroll
        for (int it = 0; it < 4; ++it) {
            const int item = it * 64 + lane;
            if (item < 240) {
                const int dj = item / 12;
                const int w4 = wave * 12 + (item - dj * 12);
                const int base = 85 * w4 + dj;   // (4*w4+j)*21 + w4 + dj
                ushort4 o;
                o.x = f2h(Dall[base]);
                o.y = f2h(Dall[base + 21]);
                o.z = f2h(Dall[base + 42]);
                o.w = f2h(Dall[base + 63]);
                *(ushort4*)(outb + (size_t)dj * 12288 + 4 * w4) = o;
            }
        }
    }
}

// ---------------------------------------------------------------------------
// Fused block v8 (device body). 4-wide tasks, HT=4, single guarded loop
// (no dual path -> low VGPR). Phase 1: (ci, wg) task computes 4w x 4h x DT d
// via fdot2 (fp32 accum); bias+leaky; f16 -> LDS sT[pos][ci], CINP odd.
// Phase 2: f16 MFMA, M=16 w-pos, N=16 co, K=32 ci.
// ---------------------------------------------------------------------------
template<int CIN, int COUT, int S, int DT, int DIN, int HIN, int WIN,
         int DO, int HO, int WO, typename TOUT>
static __device__ __forceinline__ void fused_impl(
        const u16* __restrict__ x,
        const float* __restrict__ dw_w, const float* __restrict__ dw_b,
        const float* __restrict__ pw_w, const float* __restrict__ pw_b,
        TOUT* __restrict__ y) {
    static_assert(WO % 48 == 0 && HO % 4 == 0, "tile divisibility");
    constexpr int CINP = (CIN == 20) ? 22 : 42;    // odd dword stride
    constexpr int NTASK = CIN * 12;
    constexpr int WT = WO / 48;
    constexpr int NP = S * (DT - 1) + 3;

    const int wt = blockIdx.x % WT;
    const int ht = blockIdx.x / WT;
    const int d0 = blockIdx.y * DT;
    const int b  = blockIdx.z;
    const int tid = threadIdx.x;
    const int h0 = ht * 4;
    const int wbase = wt * 48;

    __shared__ float sDW[CIN * 27];
    __shared__ float sDB[CIN];
    __shared__ u16   sT[DT * 4 * 48 * CINP + 16];

    for (int i = tid; i < CIN * 27; i += 256) sDW[i] = dw_w[i];
    for (int i = tid; i < CIN; i += 256) sDB[i] = dw_b[i];
    __syncthreads();

    // ---------------- phase 1: depthwise via fdot2 ----------------
    for (int idx = tid; idx < NTASK; idx += 256) {
        const int ci = idx / 12;
        const int wg = idx - ci * 12;
        const int w0g = wbase + wg * 4;

        half2_t KA[9], KB[9];
#pragma unroll
        for (int t = 0; t < 9; ++t) {
            const int kd = t / 3, kh = t - 3 * kd;
            const float k0 = sDW[ci * 27 + kd * 9 + kh * 3 + 0];
            const float k1 = sDW[ci * 27 + kd * 9 + kh * 3 + 1];
            const float k2 = sDW[ci * 27 + kd * 9 + kh * 3 + 2];
            half2_t a; a.x = (f16_t)k0; a.y = (f16_t)k1; KA[t] = a;
            half2_t bb;
            if constexpr (S == 1) { bb.x = (f16_t)k2; bb.y = (f16_t)0.f; }
            else                  { bb.x = (f16_t)0.f; bb.y = (f16_t)k2; }
            KB[t] = bb;
        }

        float acc[DT][4][4];
#pragma unroll
        for (int dl = 0; dl < DT; ++dl)
#pragma unroll
            for (int a = 0; a < 4; ++a)
#pragma unroll
                for (int c = 0; c < 4; ++c) acc[dl][a][c] = 0.f;

        const u16* plane0 = x + (size_t)(b * CIN + ci) * DIN * HIN * WIN;
#pragma unroll
        for (int p = 0; p < NP; ++p) {
            const int din = S * d0 - 1 + p;
            if (din < 0 || din >= DIN) continue;       // block-uniform
            const u16* pl = plane0 + (size_t)din * HIN * WIN;
#pragma unroll
            for (int r = 0; r < 3 * S + 3; ++r) {
                const int hin = h0 * S - 1 + r;
                if (hin < 0 || hin >= HIN) continue;   // block-uniform
                const u16* rowp = pl + (size_t)hin * WIN + (size_t)w0g * S;
                uint32_t PA[4], PB[4];
                if constexpr (S == 1) {
                    const uint32_t D0 = (w0g > 0) ? ldu(rowp - 2) : 0u;
                    const uint32_t D1 = ldu(rowp);
                    const uint32_t D2 = ldu(rowp + 2);
                    const uint32_t D3 = (w0g + 4 < WIN) ? ldu(rowp + 4) : 0u;
                    const uint32_t m01 = mkp(D0, D1);  // (x-1,x0)
                    const uint32_t m12 = mkp(D1, D2);  // (x1,x2)
                    const uint32_t m23 = mkp(D2, D3);  // (x3,x4)
                    PA[0] = m01; PA[1] = D1; PA[2] = m12; PA[3] = D2;
                    PB[0] = m12; PB[1] = D2; PB[2] = m23; PB[3] = D3;
                } else {
                    const uint32_t E0 = (w0g > 0) ? ldu(rowp - 2) : 0u;
                    const uint32_t E1 = ldu(rowp);
                    const uint32_t E2 = ldu(rowp + 2);
                    const uint32_t E3 = ldu(rowp + 4);
                    const uint32_t E4 = ldu(rowp + 6);
                    PA[0] = mkp(E0, E1); PA[1] = mkp(E1, E2);
                    PA[2] = mkp(E2, E3); PA[3] = mkp(E3, E4);
                    PB[0] = E1; PB[1] = E2; PB[2] = E3; PB[3] = E4;
                }
#pragma unroll
                for (int dl = 0; dl < DT; ++dl) {
                    const int kd = p - S * dl;         // folds after unroll
                    if (kd < 0 || kd > 2) continue;
#pragma unroll
                    for (int hh = 0; hh < 4; ++hh) {
                        const int kh = r - S * hh;     // folds after unroll
                        if (kh < 0 || kh > 2) continue;
                        const int t = kd * 3 + kh;
#pragma unroll
                        for (int k = 0; k < 4; ++k)
                            acc[dl][hh][k] = FDOT2(H2(PB[k]), KB[t],
                                             FDOT2(H2(PA[k]), KA[t],
                                                   acc[dl][hh][k]));
                    }
                }
            }
        }

        const float bia = sDB[ci];
#pragma unroll
        for (int dl = 0; dl < DT; ++dl) {
#pragma unroll
            for (int hh = 0; hh < 4; ++hh) {
#pragma unroll
                for (int k = 0; k < 4; ++k) {
                    const float t = acc[dl][hh][k] + bia;
                    sT[((dl * 4 + hh) * 48 + wg * 4 + k) * CINP + ci] =
                        f2h(fmaxf(t, 0.1f * t));
                }
            }
        }
    }
    __syncthreads();

    // ---------------- phase 2: pointwise via f16 MFMA ----------------
    constexpr int NT = (COUT + 15) / 16;   // co tiles
    constexpr int KH = (CIN + 31) / 32;    // K=32 chunks
    constexpr int MTW = DT * 3;            // M-tiles per wave
    const int lane = tid & 63, wave = tid >> 6;
    const int m15 = lane & 15, q = lane >> 4;

    half8_t bf[NT][KH];
    float   pb[NT];
#pragma unroll
    for (int nt = 0; nt < NT; ++nt) {
        const int co = nt * 16 + m15;
        pb[nt] = (co < COUT) ? pw_b[co] : 0.f;
#pragma unroll
        for (int kh = 0; kh < KH; ++kh) {
            union { half8_t v; f16_t e[8]; } u;
#pragma unroll
            for (int j = 0; j < 8; ++j) {
                const int ci = kh * 32 + q * 8 + j;
                u.e[j] = (co < COUT && ci < CIN)
                         ? (f16_t)pw_w[co * CIN + ci] : (f16_t)0.f;
            }
            bf[nt][kh] = u.v;
        }
    }

    const size_t planeSz = (size_t)DO * HO * WO;
    for (int mt = wave * MTW; mt < (wave + 1) * MTW; ++mt) {
        const int dl  = mt / 12;
        const int rem = mt - dl * 12;
        const int hh  = rem / 3;
        const int w0  = (rem - hh * 3) * 16;
        if (d0 + dl >= DO) continue;           // tail guard

        const int pos0 = (dl * 4 + hh) * 48 + w0 + m15;
        const u16* ap = &sT[(size_t)pos0 * CINP];
        union { uint32_t u[4]; half8_t v; } af[KH];
#pragma unroll
        for (int kh = 0; kh < KH; ++kh) {
            const int ci0 = kh * 32 + q * 8;
            af[kh].u[0] = (ci0     < CIN) ? ldu(ap + ci0)     : 0u;
            af[kh].u[1] = (ci0 + 2 < CIN) ? ldu(ap + ci0 + 2) : 0u;
            af[kh].u[2] = (ci0 + 4 < CIN) ? ldu(ap + ci0 + 4) : 0u;
            af[kh].u[3] = (ci0 + 6 < CIN) ? ldu(ap + ci0 + 6) : 0u;
        }
#pragma unroll
        for (int nt = 0; nt < NT; ++nt) {
            f32x4 acc;
            acc.x = 0.f; acc.y = 0.f; acc.z = 0.f; acc.w = 0.f;
#pragma unroll
            for (int kh = 0; kh < KH; ++kh)
                acc = __builtin_amdgcn_mfma_f32_16x16x32_f16(
                          af[kh].v, bf[nt][kh], acc, 0, 0, 0);
            const int co = nt * 16 + m15;
            if (co < COUT) {
                const float bias = pb[nt];
                TOUT* yp = y + (size_t)b * COUT * planeSz + (size_t)co * planeSz
                             + (size_t)(d0 + dl) * HO * WO
                             + (size_t)(h0 + hh) * WO + wbase + w0 + q * 4;
                float s0 = acc.x + bias, s1 = acc.y + bias;
                float s2 = acc.z + bias, s3 = acc.w + bias;
                s0 = fmaxf(s0, 0.1f * s0); s1 = fmaxf(s1, 0.1f * s1);
                s2 = fmaxf(s2, 0.1f * s2); s3 = fmaxf(s3, 0.1f * s3);
                if constexpr (sizeof(TOUT) == 4) {
                    float4 o; o.x = s0; o.y = s1; o.z = s2; o.w = s3;
                    *(float4*)yp = o;
                } else {
                    ushort4 o;
                    o.x = f2h(s0); o.y = f2h(s1); o.z = f2h(s2); o.w = f2h(s3);
                    *(ushort4*)yp = o;
                }
            }
        }
    }
}

// Named wrappers -> per-stage visibility in rocprof.
__global__ __launch_bounds__(256) void fb1_dwpw(
        const u16* __restrict__ x, const float* __restrict__ dww,
        const float* __restrict__ dwb, const float* __restrict__ pww,
        const float* __restrict__ pwb, u16* __restrict__ y) {
    fused_impl<20, 20, 1, 2, 20, 64, 192, 20, 64, 192, u16>(x, dww, dwb, pww, pwb, y);
}
__global__ __launch_bounds__(256) void fb2_dwpw(
        const u16* __restrict__ x, const float* __restrict__ dww,
        const float* __restrict__ dwb, const float* __restrict__ pww,
        const float* __restrict__ pwb, u16* __restrict__ y) {
    fused_impl<20, 40, 2, 2, 20, 64, 192, 10, 32, 96, u16>(x, dww, dwb, pww, pwb, y);
}
__global__ __launch_bounds__(256) void fb3_dwpw(
        const u16* __restrict__ x, const float* __restrict__ dww,
        const float* __restrict__ dwb, const float* __restrict__ pww,
        const float* __restrict__ pwb, u16* __restrict__ y) {
    fused_impl<40, 40, 1, 1, 10, 32, 96, 10, 32, 96, u16>(x, dww, dwb, pww, pwb, y);
}
__global__ __launch_bounds__(256) void fb4_dwpw(
        const u16* __restrict__ x, const float* __restrict__ dww,
        const float* __restrict__ dwb, const float* __restrict__ pww,
        const float* __restrict__ pwb, float* __restrict__ y) {
    fused_impl<40, 80, 2, 1, 10, 32, 96, 5, 16, 48, float>(x, dww, dwb, pww, pwb, y);
}

// ---------------------------------------------------------------------------
extern "C" void kernel_launch(void* const* d_in, const int* in_sizes, int n_in,
                              void* d_out, int out_size, void* d_ws, size_t ws_size,
                              hipStream_t stream) {
    const float* rgb  = (const float*)d_in[0];
    const float* dep  = (const float*)d_in[1];
    const float* dw1w = (const float*)d_in[2];
    const float* dw1b = (const float*)d_in[3];
    const float* pw1w = (const float*)d_in[4];
    const float* pw1b = (const float*)d_in[5];
    const float* dw2w = (const float*)d_in[6];
    const float* dw2b = (const float*)d_in[7];
    const float* pw2w = (const float*)d_in[8];
    const float* pw2b = (const float*)d_in[9];
    const float* dw3w = (const float*)d_in[10];
    const float* dw3b = (const float*)d_in[11];
    const float* pw3w = (const float*)d_in[12];
    const float* pw3b = (const float*)d_in[13];
    const float* dw4w = (const float*)d_in[14];
    const float* dw4b = (const float*)d_in[15];
    const float* pw4w = (const float*)d_in[16];
    const float* pw4b = (const float*)d_in[17];

    const size_t HALF = 78643200;
    u16* corrO = (u16*)d_ws;
    u16* rgbT  = (u16*)((char*)d_ws + HALF);
    u16* depT  = (u16*)((char*)d_ws + HALF + 12582912);
    u16* b1o   = (u16*)((char*)d_ws + HALF);   // rgbT/depT dead by then
    u16* b2o   = (u16*)d_ws;                   // corrO dead by then
    u16* b3o   = (u16*)((char*)d_ws + HALF);   // b1o dead by then
    float* outp = (float*)d_out;

    transpose_f16<<<dim3(512, 2), 256, 0, stream>>>(rgb, dep, rgbT, depT);

    corr_mfma<<<dim3(5, 64, 8), 256, 0, stream>>>(rgbT, depT, corrO);

    fb1_dwpw<<<dim3(64, 10, 8), 256, 0, stream>>>(corrO, dw1w, dw1b, pw1w, pw1b, b1o);
    fb2_dwpw<<<dim3(16, 5, 8), 256, 0, stream>>>(b1o, dw2w, dw2b, pw2w, pw2b, b2o);
    fb3_dwpw<<<dim3(16, 10, 8), 256, 0, stream>>>(b2o, dw3w, dw3b, pw3w, pw3b, b3o);
    fb4_dwpw<<<dim3(4, 5, 8), 256, 0, stream>>>(b3o, dw4w, dw4b, pw4w, pw4b, outp);
}

// Round 10
// 385.605 us; speedup vs baseline: 1.3194x; 1.0907x over previous
//
#include <hip/hip_runtime.h>
#include <cstdint>
#include <cstddef>

// ---------------------------------------------------------------------------
// feature_matching: corr(P=20, C=64) -> 4x (depthwise 3^3 + pointwise) blocks
//
// R10 = R9 geometry (occupancy-first: LDS<=21KB, VGPR small, HT=4, fb3 DT=1)
// with phase-1 restructured for memory-level parallelism: per plane, ALL row
// dwords load unconditionally into registers first (h-clamped addresses,
// zero-masks applied afterwards via cndmask), then the fdot2 compute pass.
// MLP per batch: 4 -> 24 (S=1) / 15 (S=2). No other changes.
//
// ws layout (peak 157,286,400 B):
//   [0,        78.6MB): corrO (f16)        -> later b2o (f16, 19.7MB)
//   [78.6MB,  157.3MB): rgbT+depT (f16)    -> later b1o (f16, 78.6MB)
//                                          -> later b3o (f16, 19.7MB)
// ---------------------------------------------------------------------------

typedef unsigned short u16;
typedef _Float16 f16_t;
typedef __attribute__((ext_vector_type(2))) _Float16 half2_t;
typedef __attribute__((ext_vector_type(8))) _Float16 half8_t;
typedef __attribute__((ext_vector_type(4))) float f32x4;

static __device__ inline u16 f2h(float f) {
    union { f16_t h; u16 u; } v; v.h = (f16_t)f; return v.u;
}
static __device__ inline half2_t H2(uint32_t u) {
    union { uint32_t u; half2_t h; } v; v.u = u; return v.h;
}

#if __has_builtin(__builtin_amdgcn_fdot2)
static __device__ inline float FDOT2(half2_t a, half2_t b, float c) {
    return __builtin_amdgcn_fdot2(a, b, c, false);
}
#else
static __device__ inline float FDOT2(half2_t a, half2_t b, float c) {
    return fmaf((float)a.x, (float)b.x, fmaf((float)a.y, (float)b.y, c));
}
#endif

#if __has_builtin(__builtin_amdgcn_alignbit)
static __device__ inline uint32_t mkp(uint32_t lo, uint32_t hi) {
    return __builtin_amdgcn_alignbit(hi, lo, 16);   // (lo.hi16, hi.lo16)
}
#else
static __device__ inline uint32_t mkp(uint32_t lo, uint32_t hi) {
    return (lo >> 16) | (hi << 16);
}
#endif

static __device__ inline uint32_t ldu(const u16* p) { return *(const uint32_t*)p; }

// ---------------------------------------------------------------------------
// Prepass: (b,c,h,w) fp32 -> (b,h,w,c) f16, LDS tile transpose per (b,h).
// ---------------------------------------------------------------------------
__global__ __launch_bounds__(256) void transpose_f16(
        const float* __restrict__ rgb, const float* __restrict__ dep,
        u16* __restrict__ rgbT, u16* __restrict__ depT) {
    const int bh = blockIdx.x;
    const float* src = blockIdx.y ? dep : rgb;
    u16* dst = blockIdx.y ? depT : rgbT;
    const int tid = threadIdx.x;
    const int b = bh >> 6, h = bh & 63;

    __shared__ u16 S[64 * 194];

    const float* srcb = src + (size_t)b * 786432 + (size_t)h * 192;
#pragma unroll
    for (int it = 0; it < 12; ++it) {
        const int idx = it * 256 + tid;      // 3072 = 64c x 48 float4
        const int c = idx / 48, w4 = idx - c * 48;
        const float4 v = *(const float4*)(srcb + (size_t)c * 12288 + 4 * w4);
        u16* sp = &S[c * 194 + 4 * w4];
        sp[0] = f2h(v.x); sp[1] = f2h(v.y); sp[2] = f2h(v.z); sp[3] = f2h(v.w);
    }
    __syncthreads();
    u16* dstb = dst + (size_t)bh * 192 * 64;
#pragma unroll
    for (int it = 0; it < 12; ++it) {
        const int idx = it * 256 + tid;      // 3072 = 192w x 16 c4
        const int w = idx >> 4, c4 = idx & 15;
        ushort4 o;
        o.x = S[(4 * c4 + 0) * 194 + w];
        o.y = S[(4 * c4 + 1) * 194 + w];
        o.z = S[(4 * c4 + 2) * 194 + w];
        o.w = S[(4 * c4 + 3) * 194 + w];
        *(ushort4*)(dstb + (size_t)w * 64 + 4 * c4) = o;
    }
}

// ---------------------------------------------------------------------------
// corr v3. Grid (dig=5, h=64, b=8), 256 threads (4 waves, no barriers).
// Wave owns 48 w; A-frags (rgb row) loaded once, reused over 4 di.
// ---------------------------------------------------------------------------
__global__ __launch_bounds__(256) void corr_mfma(
        const u16* __restrict__ rgbT, const u16* __restrict__ depT,
        u16* __restrict__ out) {
    const int dig = blockIdx.x, h = blockIdx.y, b = blockIdx.z;
    const int tid = threadIdx.x;
    const int lane = tid & 63, wave = tid >> 6;
    const int n = lane & 15, q = lane >> 4;

    __shared__ float Dall[4080];         // addr = w*21 + (w>>2) + dj

    const u16* Abase = rgbT + (size_t)(b * 64 + h) * 12288;
    half8_t a0[3], a1[3];
#pragma unroll
    for (int t = 0; t < 3; ++t) {
        const int w0 = wave * 48 + t * 16;
        const half8_t* Ap = (const half8_t*)(Abase + (size_t)(w0 + n) * 64 + q * 8);
        a0[t] = Ap[0];                   // c = q*8 .. q*8+7
        a1[t] = Ap[4];                   // c += 32
    }

#pragma unroll
    for (int i = 0; i < 4; ++i) {
        const int di = dig * 4 + i;
        const int hd = h + di - 10;
        u16* outb = out + ((size_t)((b * 20 + di) * 20) * 64 + h) * 192;

        if (hd < 0 || hd >= 64) {        // depth row fully in zero-pad
#pragma unroll
            for (int it = 0; it < 4; ++it) {
                const int item = it * 64 + lane;
                if (item < 240) {
                    const int dj = item / 12;
                    const int w4 = wave * 12 + (item - dj * 12);
                    *(ushort4*)(outb + (size_t)dj * 12288 + 4 * w4) =
                        make_ushort4(0, 0, 0, 0);
                }
            }
            continue;
        }

        const u16* Bbase = depT + (size_t)(b * 64 + hd) * 12288;
#pragma unroll
        for (int t = 0; t < 3; ++t) {
            const int w0 = wave * 48 + t * 16;
            f32x4 acc[3];
#pragma unroll
            for (int ut = 0; ut < 3; ++ut) {
                acc[ut].x = 0.f; acc[ut].y = 0.f; acc[ut].z = 0.f; acc[ut].w = 0.f;
            }
#pragma unroll
            for (int ut = 0; ut < 3; ++ut) {
                const int u0 = w0 + (ut - 1) * 16;
                if (u0 >= 0 && u0 <= 176) {  // wave-uniform; OOB tile stays 0
                    const half8_t* Bp = (const half8_t*)(Bbase + (size_t)(u0 + n) * 64 + q * 8);
                    acc[ut] = __builtin_amdgcn_mfma_f32_16x16x32_f16(a0[t], Bp[0], acc[ut], 0, 0, 0);
                    acc[ut] = __builtin_amdgcn_mfma_f32_16x16x32_f16(a1[t], Bp[4], acc[ut], 0, 0, 0);
                }
            }
#pragma unroll
            for (int ut = 0; ut < 3; ++ut) {
#pragma unroll
                for (int r = 0; r < 4; ++r) {
                    const int dj = 16 * ut + n - 4 * q - r - 6;
                    const int w = w0 + 4 * q + r;
                    if (dj >= 0 && dj < 20)
                        Dall[w * 21 + (w >> 2) + dj] = acc[ut][r];
                }
            }
        }
        // wave-local readout (writes above are by this wave only)
#pragma unroll
        for (int it = 0; it < 4; ++it) {
            const int item = it * 64 + lane;
            if (item < 240) {
                const int dj = item / 12;
                const int w4 = wave * 12 + (item - dj * 12);
                const int base = 85 * w4 + dj;   // (4*w4+j)*21 + w4 + dj
                ushort4 o;
                o.x = f2h(Dall[base]);
                o.y = f2h(Dall[base + 21]);
                o.z = f2h(Dall[base + 42]);
                o.w = f2h(Dall[base + 63]);
                *(ushort4*)(outb + (size_t)dj * 12288 + 4 * w4) = o;
            }
        }
    }
}

// ---------------------------------------------------------------------------
// Fused block v9 (device body). 4-wide tasks, HT=4, R9 geometry. Phase 1 now
// does a load-pass (all rows of a plane/group, unconditional, h-clamped
// addresses) then a compute-pass (cndmask zero-masks + fdot2). Batches:
// S=1 -> 24 loads, S=2 -> 15 loads per batch. Phase 2: f16 MFMA as R9.
// ---------------------------------------------------------------------------
template<int CIN, int COUT, int S, int DT, int DIN, int HIN, int WIN,
         int DO, int HO, int WO, typename TOUT>
static __device__ __forceinline__ void fused_impl(
        const u16* __restrict__ x,
        const float* __restrict__ dw_w, const float* __restrict__ dw_b,
        const float* __restrict__ pw_w, const float* __restrict__ pw_b,
        TOUT* __restrict__ y) {
    static_assert(WO % 48 == 0 && HO % 4 == 0, "tile divisibility");
    constexpr int CINP = (CIN == 20) ? 22 : 42;    // odd dword stride
    constexpr int NTASK = CIN * 12;
    constexpr int WT = WO / 48;
    constexpr int NP = S * (DT - 1) + 3;
    constexpr int ROWS = 3 * S + 3;                // 6 or 9
    constexpr int NL = (S == 1) ? 4 : 5;           // dwords per row
    constexpr int G  = (S == 1) ? 6 : 3;           // rows per load batch
    constexpr int NG = ROWS / G;

    const int wt = blockIdx.x % WT;
    const int ht = blockIdx.x / WT;
    const int d0 = blockIdx.y * DT;
    const int b  = blockIdx.z;
    const int tid = threadIdx.x;
    const int h0 = ht * 4;
    const int wbase = wt * 48;

    __shared__ float sDW[CIN * 27];
    __shared__ float sDB[CIN];
    __shared__ u16   sT[DT * 4 * 48 * CINP + 16];

    for (int i = tid; i < CIN * 27; i += 256) sDW[i] = dw_w[i];
    for (int i = tid; i < CIN; i += 256) sDB[i] = dw_b[i];
    __syncthreads();

    // ---------------- phase 1: depthwise via fdot2 ----------------
    for (int idx = tid; idx < NTASK; idx += 256) {
        const int ci = idx / 12;
        const int wg = idx - ci * 12;
        const int w0g = wbase + wg * 4;
        const int offA = (w0g > 0) ? -2 : 0;   // keeps corner load in-bounds

        half2_t KA[9], KB[9];
#pragma unroll
        for (int t = 0; t < 9; ++t) {
            const int kd = t / 3, kh = t - 3 * kd;
            const float k0 = sDW[ci * 27 + kd * 9 + kh * 3 + 0];
            const float k1 = sDW[ci * 27 + kd * 9 + kh * 3 + 1];
            const float k2 = sDW[ci * 27 + kd * 9 + kh * 3 + 2];
            half2_t a; a.x = (f16_t)k0; a.y = (f16_t)k1; KA[t] = a;
            half2_t bb;
            if constexpr (S == 1) { bb.x = (f16_t)k2; bb.y = (f16_t)0.f; }
            else                  { bb.x = (f16_t)0.f; bb.y = (f16_t)k2; }
            KB[t] = bb;
        }

        float acc[DT][4][4];
#pragma unroll
        for (int dl = 0; dl < DT; ++dl)
#pragma unroll
            for (int a = 0; a < 4; ++a)
#pragma unroll
                for (int c = 0; c < 4; ++c) acc[dl][a][c] = 0.f;

        const u16* plane0 = x + (size_t)(b * CIN + ci) * DIN * HIN * WIN;
#pragma unroll
        for (int p = 0; p < NP; ++p) {
            const int din = S * d0 - 1 + p;
            if (din < 0 || din >= DIN) continue;       // block-uniform, rare
            const u16* pl = plane0 + (size_t)din * HIN * WIN;
#pragma unroll
            for (int g = 0; g < NG; ++g) {
                // ---- load pass: all rows of this batch, unconditional ----
                uint32_t R[G][NL];
#pragma unroll
                for (int rr = 0; rr < G; ++rr) {
                    const int r = g * G + rr;
                    int hin = h0 * S - 1 + r;
                    int hc = hin < 0 ? 0 : (hin >= HIN ? HIN - 1 : hin);
                    const u16* rowp = pl + (size_t)hc * WIN + (size_t)w0g * S;
                    R[rr][0] = ldu(rowp + offA);
                    R[rr][1] = ldu(rowp);
                    R[rr][2] = ldu(rowp + 2);
                    R[rr][3] = ldu(rowp + 4);
                    if constexpr (S == 2) R[rr][4] = ldu(rowp + 6);
                }
                // ---- compute pass: masks + fdot2 ----
#pragma unroll
                for (int rr = 0; rr < G; ++rr) {
                    const int r = g * G + rr;
                    const int hin = h0 * S - 1 + r;
                    uint32_t D0 = R[rr][0], D1 = R[rr][1];
                    uint32_t D2 = R[rr][2], D3 = R[rr][3];
                    uint32_t E4 = 0;
                    if constexpr (S == 2) E4 = R[rr][4];
                    // w-edge masks (per-thread)
                    D0 = (w0g > 0) ? D0 : 0u;
                    if constexpr (S == 1) D3 = (w0g + 4 < WIN) ? D3 : 0u;
                    // h-validity: only first row (and last row for S=1) can
                    // be OOB; block-uniform runtime mask.
                    if constexpr (S == 1) {
                        if (r == 0 || r == ROWS - 1) {
                            const bool rv = (hin >= 0) && (hin < HIN);
                            if (!rv) { D0 = 0; D1 = 0; D2 = 0; D3 = 0; }
                        }
                    } else {
                        if (r == 0) {
                            const bool rv = (hin >= 0);
                            if (!rv) { D0 = 0; D1 = 0; D2 = 0; D3 = 0; E4 = 0; }
                        }
                    }
                    uint32_t PA[4], PB[4];
                    if constexpr (S == 1) {
                        const uint32_t m01 = mkp(D0, D1);  // (x-1,x0)
                        const uint32_t m12 = mkp(D1, D2);  // (x1,x2)
                        const uint32_t m23 = mkp(D2, D3);  // (x3,x4)
                        PA[0] = m01; PA[1] = D1; PA[2] = m12; PA[3] = D2;
                        PB[0] = m12; PB[1] = D2; PB[2] = m23; PB[3] = D3;
                    } else {
                        PA[0] = mkp(D0, D1); PA[1] = mkp(D1, D2);
                        PA[2] = mkp(D2, D3); PA[3] = mkp(D3, E4);
                        PB[0] = D1; PB[1] = D2; PB[2] = D3; PB[3] = E4;
                    }
#pragma unroll
                    for (int dl = 0; dl < DT; ++dl) {
                        const int kd = p - S * dl;         // folds after unroll
                        if (kd < 0 || kd > 2) continue;
#pragma unroll
                        for (int hh = 0; hh < 4; ++hh) {
                            const int kh = r - S * hh;     // folds after unroll
                            if (kh < 0 || kh > 2) continue;
                            const int t = kd * 3 + kh;
#pragma unroll
                            for (int k = 0; k < 4; ++k)
                                acc[dl][hh][k] = FDOT2(H2(PB[k]), KB[t],
                                                 FDOT2(H2(PA[k]), KA[t],
                                                       acc[dl][hh][k]));
                        }
                    }
                }
            }
        }

        const float bia = sDB[ci];
#pragma unroll
        for (int dl = 0; dl < DT; ++dl) {
#pragma unroll
            for (int hh = 0; hh < 4; ++hh) {
#pragma unroll
                for (int k = 0; k < 4; ++k) {
                    const float t = acc[dl][hh][k] + bia;
                    sT[((dl * 4 + hh) * 48 + wg * 4 + k) * CINP + ci] =
                        f2h(fmaxf(t, 0.1f * t));
                }
            }
        }
    }
    __syncthreads();

    // ---------------- phase 2: pointwise via f16 MFMA ----------------
    constexpr int NT = (COUT + 15) / 16;   // co tiles
    constexpr int KH = (CIN + 31) / 32;    // K=32 chunks
    constexpr int MTW = DT * 3;            // M-tiles per wave
    const int lane = tid & 63, wave = tid >> 6;
    const int m15 = lane & 15, q = lane >> 4;

    half8_t bf[NT][KH];
    float   pb[NT];
#pragma unroll
    for (int nt = 0; nt < NT; ++nt) {
        const int co = nt * 16 + m15;
        pb[nt] = (co < COUT) ? pw_b[co] : 0.f;
#pragma unroll
        for (int kh = 0; kh < KH; ++kh) {
            union { half8_t v; f16_t e[8]; } u;
#pragma unroll
            for (int j = 0; j < 8; ++j) {
                const int ci = kh * 32 + q * 8 + j;
                u.e[j] = (co < COUT && ci < CIN)
                         ? (f16_t)pw_w[co * CIN + ci] : (f16_t)0.f;
            }
            bf[nt][kh] = u.v;
        }
    }

    const size_t planeSz = (size_t)DO * HO * WO;
    for (int mt = wave * MTW; mt < (wave + 1) * MTW; ++mt) {
        const int dl  = mt / 12;
        const int rem = mt - dl * 12;
        const int hh  = rem / 3;
        const int w0  = (rem - hh * 3) * 16;
        if (d0 + dl >= DO) continue;           // tail guard

        const int pos0 = (dl * 4 + hh) * 48 + w0 + m15;
        const u16* ap = &sT[(size_t)pos0 * CINP];
        union { uint32_t u[4]; half8_t v; } af[KH];
#pragma unroll
        for (int kh = 0; kh < KH; ++kh) {
            const int ci0 = kh * 32 + q * 8;
            af[kh].u[0] = (ci0     < CIN) ? ldu(ap + ci0)     : 0u;
            af[kh].u[1] = (ci0 + 2 < CIN) ? ldu(ap + ci0 + 2) : 0u;
            af[kh].u[2] = (ci0 + 4 < CIN) ? ldu(ap + ci0 + 4) : 0u;
            af[kh].u[3] = (ci0 + 6 < CIN) ? ldu(ap + ci0 + 6) : 0u;
        }
#pragma unroll
        for (int nt = 0; nt < NT; ++nt) {
            f32x4 acc;
            acc.x = 0.f; acc.y = 0.f; acc.z = 0.f; acc.w = 0.f;
#pragma unroll
            for (int kh = 0; kh < KH; ++kh)
                acc = __builtin_amdgcn_mfma_f32_16x16x32_f16(
                          af[kh].v, bf[nt][kh], acc, 0, 0, 0);
            const int co = nt * 16 + m15;
            if (co < COUT) {
                const float bias = pb[nt];
                TOUT* yp = y + (size_t)b * COUT * planeSz + (size_t)co * planeSz
                             + (size_t)(d0 + dl) * HO * WO
                             + (size_t)(h0 + hh) * WO + wbase + w0 + q * 4;
                float s0 = acc.x + bias, s1 = acc.y + bias;
                float s2 = acc.z + bias, s3 = acc.w + bias;
                s0 = fmaxf(s0, 0.1f * s0); s1 = fmaxf(s1, 0.1f * s1);
                s2 = fmaxf(s2, 0.1f * s2); s3 = fmaxf(s3, 0.1f * s3);
                if constexpr (sizeof(TOUT) == 4) {
                    float4 o; o.x = s0; o.y = s1; o.z = s2; o.w = s3;
                    *(float4*)yp = o;
                } else {
                    ushort4 o;
                    o.x = f2h(s0); o.y = f2h(s1); o.z = f2h(s2); o.w = f2h(s3);
                    *(ushort4*)yp = o;
                }
            }
        }
    }
}

// Named wrappers -> per-stage visibility in rocprof.
__global__ __launch_bounds__(256) void fb1_dwpw(
        const u16* __restrict__ x, const float* __restrict__ dww,
        const float* __restrict__ dwb, const float* __restrict__ pww,
        const float* __restrict__ pwb, u16* __restrict__ y) {
    fused_impl<20, 20, 1, 2, 20, 64, 192, 20, 64, 192, u16>(x, dww, dwb, pww, pwb, y);
}
__global__ __launch_bounds__(256) void fb2_dwpw(
        const u16* __restrict__ x, const float* __restrict__ dww,
        const float* __restrict__ dwb, const float* __restrict__ pww,
        const float* __restrict__ pwb, u16* __restrict__ y) {
    fused_impl<20, 40, 2, 2, 20, 64, 192, 10, 32, 96, u16>(x, dww, dwb, pww, pwb, y);
}
__global__ __launch_bounds__(256) void fb3_dwpw(
        const u16* __restrict__ x, const float* __restrict__ dww,
        const float* __restrict__ dwb, const float* __restrict__ pww,
        const float* __restrict__ pwb, u16* __restrict__ y) {
    fused_impl<40, 40, 1, 1, 10, 32, 96, 10, 32, 96, u16>(x, dww, dwb, pww, pwb, y);
}
__global__ __launch_bounds__(256) void fb4_dwpw(
        const u16* __restrict__ x, const float* __restrict__ dww,
        const float* __restrict__ dwb, const float* __restrict__ pww,
        const float* __restrict__ pwb, float* __restrict__ y) {
    fused_impl<40, 80, 2, 1, 10, 32, 96, 5, 16, 48, float>(x, dww, dwb, pww, pwb, y);
}

// ---------------------------------------------------------------------------
extern "C" void kernel_launch(void* const* d_in, const int* in_sizes, int n_in,
                              void* d_out, int out_size, void* d_ws, size_t ws_size,
                              hipStream_t stream) {
    const float* rgb  = (const float*)d_in[0];
    const float* dep  = (const float*)d_in[1];
    const float* dw1w = (const float*)d_in[2];
    const float* dw1b = (const float*)d_in[3];
    const float* pw1w = (const float*)d_in[4];
    const float* pw1b = (const float*)d_in[5];
    const float* dw2w = (const float*)d_in[6];
    const float* dw2b = (const float*)d_in[7];
    const float* pw2w = (const float*)d_in[8];
    const float* pw2b = (const float*)d_in[9];
    const float* dw3w = (const float*)d_in[10];
    const float* dw3b = (const float*)d_in[11];
    const float* pw3w = (const float*)d_in[12];
    const float* pw3b = (const float*)d_in[13];
    const float* dw4w = (const float*)d_in[14];
    const float* dw4b = (const float*)d_in[15];
    const float* pw4w = (const float*)d_in[16];
    const float* pw4b = (const float*)d_in[17];

    const size_t HALF = 78643200;
    u16* corrO = (u16*)d_ws;
    u16* rgbT  = (u16*)((char*)d_ws + HALF);
    u16* depT  = (u16*)((char*)d_ws + HALF + 12582912);
    u16* b1o   = (u16*)((char*)d_ws + HALF);   // rgbT/depT dead by then
    u16* b2o   = (u16*)d_ws;                   // corrO dead by then
    u16* b3o   = (u16*)((char*)d_ws + HALF);   // b1o dead by then
    float* outp = (float*)d_out;

    transpose_f16<<<dim3(512, 2), 256, 0, stream>>>(rgb, dep, rgbT, depT);

    corr_mfma<<<dim3(5, 64, 8), 256, 0, stream>>>(rgbT, depT, corrO);

    fb1_dwpw<<<dim3(64, 10, 8), 256, 0, stream>>>(corrO, dw1w, dw1b, pw1w, pw1b, b1o);
    fb2_dwpw<<<dim3(16, 5, 8), 256, 0, stream>>>(b1o, dw2w, dw2b, pw2w, pw2b, b2o);
    fb3_dwpw<<<dim3(16, 10, 8), 256, 0, stream>>>(b2o, dw3w, dw3b, pw3w, pw3b, b3o);
    fb4_dwpw<<<dim3(4, 5, 8), 256, 0, stream>>>(b3o, dw4w, dw4b, pw4w, pw4b, outp);
}

// Round 11
// 381.156 us; speedup vs baseline: 1.3348x; 1.0117x over previous
//
#include <hip/hip_runtime.h>
#include <cstdint>
#include <cstddef>

// ---------------------------------------------------------------------------
// feature_matching: corr(P=20, C=64) -> 4x (depthwise 3^3 + pointwise) blocks
//
// R11 = R10 + XCD-aware swizzle for corr_mfma. R10 counters: corr FETCH
// 157.5 MB vs 25 MB ideal -- dep rows reused by 20 (h,di) blocks that land
// on different XCDs (private L2s refetch ~8x). Remap blockIdx so one h-band
// (h>>3) stays on one XCD (round-robin idx%8 assumption): idx = band + 8*j,
// j = dig + 5*((h&7) + 8*b), b slowest -> ~0.7 MB sliding depT window per b
// fits 4 MB per-XCD L2. Pure index permutation; locality-only effect.
//
// ws layout (peak 157,286,400 B):
//   [0,        78.6MB): corrO (f16)        -> later b2o (f16, 19.7MB)
//   [78.6MB,  157.3MB): rgbT+depT (f16)    -> later b1o (f16, 78.6MB)
//                                          -> later b3o (f16, 19.7MB)
// ---------------------------------------------------------------------------

typedef unsigned short u16;
typedef _Float16 f16_t;
typedef __attribute__((ext_vector_type(2))) _Float16 half2_t;
typedef __attribute__((ext_vector_type(8))) _Float16 half8_t;
typedef __attribute__((ext_vector_type(4))) float f32x4;

static __device__ inline u16 f2h(float f) {
    union { f16_t h; u16 u; } v; v.h = (f16_t)f; return v.u;
}
static __device__ inline half2_t H2(uint32_t u) {
    union { uint32_t u; half2_t h; } v; v.u = u; return v.h;
}

#if __has_builtin(__builtin_amdgcn_fdot2)
static __device__ inline float FDOT2(half2_t a, half2_t b, float c) {
    return __builtin_amdgcn_fdot2(a, b, c, false);
}
#else
static __device__ inline float FDOT2(half2_t a, half2_t b, float c) {
    return fmaf((float)a.x, (float)b.x, fmaf((float)a.y, (float)b.y, c));
}
#endif

#if __has_builtin(__builtin_amdgcn_alignbit)
static __device__ inline uint32_t mkp(uint32_t lo, uint32_t hi) {
    return __builtin_amdgcn_alignbit(hi, lo, 16);   // (lo.hi16, hi.lo16)
}
#else
static __device__ inline uint32_t mkp(uint32_t lo, uint32_t hi) {
    return (lo >> 16) | (hi << 16);
}
#endif

static __device__ inline uint32_t ldu(const u16* p) { return *(const uint32_t*)p; }

// ---------------------------------------------------------------------------
// Prepass: (b,c,h,w) fp32 -> (b,h,w,c) f16, LDS tile transpose per (b,h).
// ---------------------------------------------------------------------------
__global__ __launch_bounds__(256) void transpose_f16(
        const float* __restrict__ rgb, const float* __restrict__ dep,
        u16* __restrict__ rgbT, u16* __restrict__ depT) {
    const int bh = blockIdx.x;
    const float* src = blockIdx.y ? dep : rgb;
    u16* dst = blockIdx.y ? depT : rgbT;
    const int tid = threadIdx.x;
    const int b = bh >> 6, h = bh & 63;

    __shared__ u16 S[64 * 194];

    const float* srcb = src + (size_t)b * 786432 + (size_t)h * 192;
#pragma unroll
    for (int it = 0; it < 12; ++it) {
        const int idx = it * 256 + tid;      // 3072 = 64c x 48 float4
        const int c = idx / 48, w4 = idx - c * 48;
        const float4 v = *(const float4*)(srcb + (size_t)c * 12288 + 4 * w4);
        u16* sp = &S[c * 194 + 4 * w4];
        sp[0] = f2h(v.x); sp[1] = f2h(v.y); sp[2] = f2h(v.z); sp[3] = f2h(v.w);
    }
    __syncthreads();
    u16* dstb = dst + (size_t)bh * 192 * 64;
#pragma unroll
    for (int it = 0; it < 12; ++it) {
        const int idx = it * 256 + tid;      // 3072 = 192w x 16 c4
        const int w = idx >> 4, c4 = idx & 15;
        ushort4 o;
        o.x = S[(4 * c4 + 0) * 194 + w];
        o.y = S[(4 * c4 + 1) * 194 + w];
        o.z = S[(4 * c4 + 2) * 194 + w];
        o.w = S[(4 * c4 + 3) * 194 + w];
        *(ushort4*)(dstb + (size_t)w * 64 + 4 * c4) = o;
    }
}

// ---------------------------------------------------------------------------
// corr v4. Flat grid 2560, XCD-band swizzle:
//   band = idx & 7 (intended XCD), j = idx >> 3,
//   dig = j % 5, h = band*8 + (j/5 & 7), b = j/40.
// 256 threads (4 waves, no barriers). Wave owns 48 w; A-frags loaded once,
// reused over 4 di. Per di: banded Z via f16 MFMA -> wave-private Dall
// scatter in (w,dj) coords -> coalesced ushort4 store.
// ---------------------------------------------------------------------------
__global__ __launch_bounds__(256) void corr_mfma(
        const u16* __restrict__ rgbT, const u16* __restrict__ depT,
        u16* __restrict__ out) {
    const int idx = blockIdx.x;
    const int band = idx & 7;
    const int j    = idx >> 3;
    const int dig  = j % 5;
    const int rest = j / 5;          // 0..63
    const int h    = band * 8 + (rest & 7);
    const int b    = rest >> 3;
    const int tid = threadIdx.x;
    const int lane = tid & 63, wave = tid >> 6;
    const int n = lane & 15, q = lane >> 4;

    __shared__ float Dall[4080];         // addr = w*21 + (w>>2) + dj

    const u16* Abase = rgbT + (size_t)(b * 64 + h) * 12288;
    half8_t a0[3], a1[3];
#pragma unroll
    for (int t = 0; t < 3; ++t) {
        const int w0 = wave * 48 + t * 16;
        const half8_t* Ap = (const half8_t*)(Abase + (size_t)(w0 + n) * 64 + q * 8);
        a0[t] = Ap[0];                   // c = q*8 .. q*8+7
        a1[t] = Ap[4];                   // c += 32
    }

#pragma unroll
    for (int i = 0; i < 4; ++i) {
        const int di = dig * 4 + i;
        const int hd = h + di - 10;
        u16* outb = out + ((size_t)((b * 20 + di) * 20) * 64 + h) * 192;

        if (hd < 0 || hd >= 64) {        // depth row fully in zero-pad
#pragma unroll
            for (int it = 0; it < 4; ++it) {
                const int item = it * 64 + lane;
                if (item < 240) {
                    const int dj = item / 12;
                    const int w4 = wave * 12 + (item - dj * 12);
                    *(ushort4*)(outb + (size_t)dj * 12288 + 4 * w4) =
                        make_ushort4(0, 0, 0, 0);
                }
            }
            continue;
        }

        const u16* Bbase = depT + (size_t)(b * 64 + hd) * 12288;
#pragma unroll
        for (int t = 0; t < 3; ++t) {
            const int w0 = wave * 48 + t * 16;
            f32x4 acc[3];
#pragma unroll
            for (int ut = 0; ut < 3; ++ut) {
                acc[ut].x = 0.f; acc[ut].y = 0.f; acc[ut].z = 0.f; acc[ut].w = 0.f;
            }
#pragma unroll
            for (int ut = 0; ut < 3; ++ut) {
                const int u0 = w0 + (ut - 1) * 16;
                if (u0 >= 0 && u0 <= 176) {  // wave-uniform; OOB tile stays 0
                    const half8_t* Bp = (const half8_t*)(Bbase + (size_t)(u0 + n) * 64 + q * 8);
                    acc[ut] = __builtin_amdgcn_mfma_f32_16x16x32_f16(a0[t], Bp[0], acc[ut], 0, 0, 0);
                    acc[ut] = __builtin_amdgcn_mfma_f32_16x16x32_f16(a1[t], Bp[4], acc[ut], 0, 0, 0);
                }
            }
#pragma unroll
            for (int ut = 0; ut < 3; ++ut) {
#pragma unroll
                for (int r = 0; r < 4; ++r) {
                    const int dj = 16 * ut + n - 4 * q - r - 6;
                    const int w = w0 + 4 * q + r;
                    if (dj >= 0 && dj < 20)
                        Dall[w * 21 + (w >> 2) + dj] = acc[ut][r];
                }
            }
        }
        // wave-local readout (writes above are by this wave only)
#pragma unroll
        for (int it = 0; it < 4; ++it) {
            const int item = it * 64 + lane;
            if (item < 240) {
                const int dj = item / 12;
                const int w4 = wave * 12 + (item - dj * 12);
                const int base = 85 * w4 + dj;   // (4*w4+j)*21 + w4 + dj
                ushort4 o;
                o.x = f2h(Dall[base]);
                o.y = f2h(Dall[base + 21]);
                o.z = f2h(Dall[base + 42]);
                o.w = f2h(Dall[base + 63]);
                *(ushort4*)(outb + (size_t)dj * 12288 + 4 * w4) = o;
            }
        }
    }
}

// ---------------------------------------------------------------------------
// Fused block v9 (device body). 4-wide tasks, HT=4, R9 geometry. Phase 1:
// load-pass (all rows of a plane/group, unconditional, h-clamped addresses)
// then compute-pass (masks + fdot2). Phase 2: f16 MFMA pointwise.
// ---------------------------------------------------------------------------
template<int CIN, int COUT, int S, int DT, int DIN, int HIN, int WIN,
         int DO, int HO, int WO, typename TOUT>
static __device__ __forceinline__ void fused_impl(
        const u16* __restrict__ x,
        const float* __restrict__ dw_w, const float* __restrict__ dw_b,
        const float* __restrict__ pw_w, const float* __restrict__ pw_b,
        TOUT* __restrict__ y) {
    static_assert(WO % 48 == 0 && HO % 4 == 0, "tile divisibility");
    constexpr int CINP = (CIN == 20) ? 22 : 42;    // odd dword stride
    constexpr int NTASK = CIN * 12;
    constexpr int WT = WO / 48;
    constexpr int NP = S * (DT - 1) + 3;
    constexpr int ROWS = 3 * S + 3;                // 6 or 9
    constexpr int NL = (S == 1) ? 4 : 5;           // dwords per row
    constexpr int G  = (S == 1) ? 6 : 3;           // rows per load batch
    constexpr int NG = ROWS / G;

    const int wt = blockIdx.x % WT;
    const int ht = blockIdx.x / WT;
    const int d0 = blockIdx.y * DT;
    const int b  = blockIdx.z;
    const int tid = threadIdx.x;
    const int h0 = ht * 4;
    const int wbase = wt * 48;

    __shared__ float sDW[CIN * 27];
    __shared__ float sDB[CIN];
    __shared__ u16   sT[DT * 4 * 48 * CINP + 16];

    for (int i = tid; i < CIN * 27; i += 256) sDW[i] = dw_w[i];
    for (int i = tid; i < CIN; i += 256) sDB[i] = dw_b[i];
    __syncthreads();

    // ---------------- phase 1: depthwise via fdot2 ----------------
    for (int idx = tid; idx < NTASK; idx += 256) {
        const int ci = idx / 12;
        const int wg = idx - ci * 12;
        const int w0g = wbase + wg * 4;
        const int offA = (w0g > 0) ? -2 : 0;   // keeps corner load in-bounds

        half2_t KA[9], KB[9];
#pragma unroll
        for (int t = 0; t < 9; ++t) {
            const int kd = t / 3, kh = t - 3 * kd;
            const float k0 = sDW[ci * 27 + kd * 9 + kh * 3 + 0];
            const float k1 = sDW[ci * 27 + kd * 9 + kh * 3 + 1];
            const float k2 = sDW[ci * 27 + kd * 9 + kh * 3 + 2];
            half2_t a; a.x = (f16_t)k0; a.y = (f16_t)k1; KA[t] = a;
            half2_t bb;
            if constexpr (S == 1) { bb.x = (f16_t)k2; bb.y = (f16_t)0.f; }
            else                  { bb.x = (f16_t)0.f; bb.y = (f16_t)k2; }
            KB[t] = bb;
        }

        float acc[DT][4][4];
#pragma unroll
        for (int dl = 0; dl < DT; ++dl)
#pragma unroll
            for (int a = 0; a < 4; ++a)
#pragma unroll
                for (int c = 0; c < 4; ++c) acc[dl][a][c] = 0.f;

        const u16* plane0 = x + (size_t)(b * CIN + ci) * DIN * HIN * WIN;
#pragma unroll
        for (int p = 0; p < NP; ++p) {
            const int din = S * d0 - 1 + p;
            if (din < 0 || din >= DIN) continue;       // block-uniform, rare
            const u16* pl = plane0 + (size_t)din * HIN * WIN;
#pragma unroll
            for (int g = 0; g < NG; ++g) {
                // ---- load pass: all rows of this batch, unconditional ----
                uint32_t R[G][NL];
#pragma unroll
                for (int rr = 0; rr < G; ++rr) {
                    const int r = g * G + rr;
                    int hin = h0 * S - 1 + r;
                    int hc = hin < 0 ? 0 : (hin >= HIN ? HIN - 1 : hin);
                    const u16* rowp = pl + (size_t)hc * WIN + (size_t)w0g * S;
                    R[rr][0] = ldu(rowp + offA);
                    R[rr][1] = ldu(rowp);
                    R[rr][2] = ldu(rowp + 2);
                    R[rr][3] = ldu(rowp + 4);
                    if constexpr (S == 2) R[rr][4] = ldu(rowp + 6);
                }
                // ---- compute pass: masks + fdot2 ----
#pragma unroll
                for (int rr = 0; rr < G; ++rr) {
                    const int r = g * G + rr;
                    const int hin = h0 * S - 1 + r;
                    uint32_t D0 = R[rr][0], D1 = R[rr][1];
                    uint32_t D2 = R[rr][2], D3 = R[rr][3];
                    uint32_t E4 = 0;
                    if constexpr (S == 2) E4 = R[rr][4];
                    // w-edge masks (per-thread)
                    D0 = (w0g > 0) ? D0 : 0u;
                    if constexpr (S == 1) D3 = (w0g + 4 < WIN) ? D3 : 0u;
                    // h-validity: only boundary rows can be OOB.
                    if constexpr (S == 1) {
                        if (r == 0 || r == ROWS - 1) {
                            const bool rv = (hin >= 0) && (hin < HIN);
                            if (!rv) { D0 = 0; D1 = 0; D2 = 0; D3 = 0; }
                        }
                    } else {
                        if (r == 0) {
                            const bool rv = (hin >= 0);
                            if (!rv) { D0 = 0; D1 = 0; D2 = 0; D3 = 0; E4 = 0; }
                        }
                    }
                    uint32_t PA[4], PB[4];
                    if constexpr (S == 1) {
                        const uint32_t m01 = mkp(D0, D1);  // (x-1,x0)
                        const uint32_t m12 = mkp(D1, D2);  // (x1,x2)
                        const uint32_t m23 = mkp(D2, D3);  // (x3,x4)
                        PA[0] = m01; PA[1] = D1; PA[2] = m12; PA[3] = D2;
                        PB[0] = m12; PB[1] = D2; PB[2] = m23; PB[3] = D3;
                    } else {
                        PA[0] = mkp(D0, D1); PA[1] = mkp(D1, D2);
                        PA[2] = mkp(D2, D3); PA[3] = mkp(D3, E4);
                        PB[0] = D1; PB[1] = D2; PB[2] = D3; PB[3] = E4;
                    }
#pragma unroll
                    for (int dl = 0; dl < DT; ++dl) {
                        const int kd = p - S * dl;         // folds after unroll
                        if (kd < 0 || kd > 2) continue;
#pragma unroll
                        for (int hh = 0; hh < 4; ++hh) {
                            const int kh = r - S * hh;     // folds after unroll
                            if (kh < 0 || kh > 2) continue;
                            const int t = kd * 3 + kh;
#pragma unroll
                            for (int k = 0; k < 4; ++k)
                                acc[dl][hh][k] = FDOT2(H2(PB[k]), KB[t],
                                                 FDOT2(H2(PA[k]), KA[t],
                                                       acc[dl][hh][k]));
                        }
                    }
                }
            }
        }

        const float bia = sDB[ci];
#pragma unroll
        for (int dl = 0; dl < DT; ++dl) {
#pragma unroll
            for (int hh = 0; hh < 4; ++hh) {
#pragma unroll
                for (int k = 0; k < 4; ++k) {
                    const float t = acc[dl][hh][k] + bia;
                    sT[((dl * 4 + hh) * 48 + wg * 4 + k) * CINP + ci] =
                        f2h(fmaxf(t, 0.1f * t));
                }
            }
        }
    }
    __syncthreads();

    // ---------------- phase 2: pointwise via f16 MFMA ----------------
    constexpr int NT = (COUT + 15) / 16;   // co tiles
    constexpr int KH = (CIN + 31) / 32;    // K=32 chunks
    constexpr int MTW = DT * 3;            // M-tiles per wave
    const int lane = tid & 63, wave = tid >> 6;
    const int m15 = lane & 15, q = lane >> 4;

    half8_t bf[NT][KH];
    float   pb[NT];
#pragma unroll
    for (int nt = 0; nt < NT; ++nt) {
        const int co = nt * 16 + m15;
        pb[nt] = (co < COUT) ? pw_b[co] : 0.f;
#pragma unroll
        for (int kh = 0; kh < KH; ++kh) {
            union { half8_t v; f16_t e[8]; } u;
#pragma unroll
            for (int j = 0; j < 8; ++j) {
                const int ci = kh * 32 + q * 8 + j;
                u.e[j] = (co < COUT && ci < CIN)
                         ? (f16_t)pw_w[co * CIN + ci] : (f16_t)0.f;
            }
            bf[nt][kh] = u.v;
        }
    }

    const size_t planeSz = (size_t)DO * HO * WO;
    for (int mt = wave * MTW; mt < (wave + 1) * MTW; ++mt) {
        const int dl  = mt / 12;
        const int rem = mt - dl * 12;
        const int hh  = rem / 3;
        const int w0  = (rem - hh * 3) * 16;
        if (d0 + dl >= DO) continue;           // tail guard

        const int pos0 = (dl * 4 + hh) * 48 + w0 + m15;
        const u16* ap = &sT[(size_t)pos0 * CINP];
        union { uint32_t u[4]; half8_t v; } af[KH];
#pragma unroll
        for (int kh = 0; kh < KH; ++kh) {
            const int ci0 = kh * 32 + q * 8;
            af[kh].u[0] = (ci0     < CIN) ? ldu(ap + ci0)     : 0u;
            af[kh].u[1] = (ci0 + 2 < CIN) ? ldu(ap + ci0 + 2) : 0u;
            af[kh].u[2] = (ci0 + 4 < CIN) ? ldu(ap + ci0 + 4) : 0u;
            af[kh].u[3] = (ci0 + 6 < CIN) ? ldu(ap + ci0 + 6) : 0u;
        }
#pragma unroll
        for (int nt = 0; nt < NT; ++nt) {
            f32x4 acc;
            acc.x = 0.f; acc.y = 0.f; acc.z = 0.f; acc.w = 0.f;
#pragma unroll
            for (int kh = 0; kh < KH; ++kh)
                acc = __builtin_amdgcn_mfma_f32_16x16x32_f16(
                          af[kh].v, bf[nt][kh], acc, 0, 0, 0);
            const int co = nt * 16 + m15;
            if (co < COUT) {
                const float bias = pb[nt];
                TOUT* yp = y + (size_t)b * COUT * planeSz + (size_t)co * planeSz
                             + (size_t)(d0 + dl) * HO * WO
                             + (size_t)(h0 + hh) * WO + wbase + w0 + q * 4;
                float s0 = acc.x + bias, s1 = acc.y + bias;
                float s2 = acc.z + bias, s3 = acc.w + bias;
                s0 = fmaxf(s0, 0.1f * s0); s1 = fmaxf(s1, 0.1f * s1);
                s2 = fmaxf(s2, 0.1f * s2); s3 = fmaxf(s3, 0.1f * s3);
                if constexpr (sizeof(TOUT) == 4) {
                    float4 o; o.x = s0; o.y = s1; o.z = s2; o.w = s3;
                    *(float4*)yp = o;
                } else {
                    ushort4 o;
                    o.x = f2h(s0); o.y = f2h(s1); o.z = f2h(s2); o.w = f2h(s3);
                    *(ushort4*)yp = o;
                }
            }
        }
    }
}

// Named wrappers -> per-stage visibility in rocprof.
__global__ __launch_bounds__(256) void fb1_dwpw(
        const u16* __restrict__ x, const float* __restrict__ dww,
        const float* __restrict__ dwb, const float* __restrict__ pww,
        const float* __restrict__ pwb, u16* __restrict__ y) {
    fused_impl<20, 20, 1, 2, 20, 64, 192, 20, 64, 192, u16>(x, dww, dwb, pww, pwb, y);
}
__global__ __launch_bounds__(256) void fb2_dwpw(
        const u16* __restrict__ x, const float* __restrict__ dww,
        const float* __restrict__ dwb, const float* __restrict__ pww,
        const float* __restrict__ pwb, u16* __restrict__ y) {
    fused_impl<20, 40, 2, 2, 20, 64, 192, 10, 32, 96, u16>(x, dww, dwb, pww, pwb, y);
}
__global__ __launch_bounds__(256) void fb3_dwpw(
        const u16* __restrict__ x, const float* __restrict__ dww,
        const float* __restrict__ dwb, const float* __restrict__ pww,
        const float* __restrict__ pwb, u16* __restrict__ y) {
    fused_impl<40, 40, 1, 1, 10, 32, 96, 10, 32, 96, u16>(x, dww, dwb, pww, pwb, y);
}
__global__ __launch_bounds__(256) void fb4_dwpw(
        const u16* __restrict__ x, const float* __restrict__ dww,
        const float* __restrict__ dwb, const float* __restrict__ pww,
        const float* __restrict__ pwb, float* __restrict__ y) {
    fused_impl<40, 80, 2, 1, 10, 32, 96, 5, 16, 48, float>(x, dww, dwb, pww, pwb, y);
}

// ---------------------------------------------------------------------------
extern "C" void kernel_launch(void* const* d_in, const int* in_sizes, int n_in,
                              void* d_out, int out_size, void* d_ws, size_t ws_size,
                              hipStream_t stream) {
    const float* rgb  = (const float*)d_in[0];
    const float* dep  = (const float*)d_in[1];
    const float* dw1w = (const float*)d_in[2];
    const float* dw1b = (const float*)d_in[3];
    const float* pw1w = (const float*)d_in[4];
    const float* pw1b = (const float*)d_in[5];
    const float* dw2w = (const float*)d_in[6];
    const float* dw2b = (const float*)d_in[7];
    const float* pw2w = (const float*)d_in[8];
    const float* pw2b = (const float*)d_in[9];
    const float* dw3w = (const float*)d_in[10];
    const float* dw3b = (const float*)d_in[11];
    const float* pw3w = (const float*)d_in[12];
    const float* pw3b = (const float*)d_in[13];
    const float* dw4w = (const float*)d_in[14];
    const float* dw4b = (const float*)d_in[15];
    const float* pw4w = (const float*)d_in[16];
    const float* pw4b = (const float*)d_in[17];

    const size_t HALF = 78643200;
    u16* corrO = (u16*)d_ws;
    u16* rgbT  = (u16*)((char*)d_ws + HALF);
    u16* depT  = (u16*)((char*)d_ws + HALF + 12582912);
    u16* b1o   = (u16*)((char*)d_ws + HALF);   // rgbT/depT dead by then
    u16* b2o   = (u16*)d_ws;                   // corrO dead by then
    u16* b3o   = (u16*)((char*)d_ws + HALF);   // b1o dead by then
    float* outp = (float*)d_out;

    transpose_f16<<<dim3(512, 2), 256, 0, stream>>>(rgb, dep, rgbT, depT);

    corr_mfma<<<dim3(2560), 256, 0, stream>>>(rgbT, depT, corrO);

    fb1_dwpw<<<dim3(64, 10, 8), 256, 0, stream>>>(corrO, dw1w, dw1b, pw1w, pw1b, b1o);
    fb2_dwpw<<<dim3(16, 5, 8), 256, 0, stream>>>(b1o, dw2w, dw2b, pw2w, pw2b, b2o);
    fb3_dwpw<<<dim3(16, 10, 8), 256, 0, stream>>>(b2o, dw3w, dw3b, pw3w, pw3b, b3o);
    fb4_dwpw<<<dim3(4, 5, 8), 256, 0, stream>>>(b3o, dw4w, dw4b, pw4w, pw4b, outp);
}

// Round 12
// 353.108 us; speedup vs baseline: 1.4408x; 1.0794x over previous
//
#include <hip/hip_runtime.h>
#include <cstdint>
#include <cstddef>

// ---------------------------------------------------------------------------
// feature_matching: corr(P=20, C=64) -> 4x (depthwise 3^3 + pointwise) blocks
//
// R12 = R11 with corr v5 (latency-chain fix). R11 showed the swizzle fixed
// traffic (157->40 MB) but dur unchanged -> corr is dependency-chain bound:
// per-di serial {B-load -> MFMA -> scatter -> lgkm drain -> readout -> store}
// with Dall WAR forcing the drain. v5: per-di u16 Dall banks D4[4][4080]
// (f2h moved to scatter; no WAR), ONE merged readout at the end (single
// lgkm wait, 64 independent ds_reads), and B-tile dedupe 9->5 pairs loaded
// up front (MLP 10). LDS 32.6KB caps at 4 blk/CU; VGPR ~90 < 128 ok.
// fb kernels unchanged from R11.
//
// ws layout (peak 157,286,400 B):
//   [0,        78.6MB): corrO (f16)        -> later b2o (f16, 19.7MB)
//   [78.6MB,  157.3MB): rgbT+depT (f16)    -> later b1o (f16, 78.6MB)
//                                          -> later b3o (f16, 19.7MB)
// ---------------------------------------------------------------------------

typedef unsigned short u16;
typedef _Float16 f16_t;
typedef __attribute__((ext_vector_type(2))) _Float16 half2_t;
typedef __attribute__((ext_vector_type(8))) _Float16 half8_t;
typedef __attribute__((ext_vector_type(4))) float f32x4;

static __device__ inline u16 f2h(float f) {
    union { f16_t h; u16 u; } v; v.h = (f16_t)f; return v.u;
}
static __device__ inline half2_t H2(uint32_t u) {
    union { uint32_t u; half2_t h; } v; v.u = u; return v.h;
}

#if __has_builtin(__builtin_amdgcn_fdot2)
static __device__ inline float FDOT2(half2_t a, half2_t b, float c) {
    return __builtin_amdgcn_fdot2(a, b, c, false);
}
#else
static __device__ inline float FDOT2(half2_t a, half2_t b, float c) {
    return fmaf((float)a.x, (float)b.x, fmaf((float)a.y, (float)b.y, c));
}
#endif

#if __has_builtin(__builtin_amdgcn_alignbit)
static __device__ inline uint32_t mkp(uint32_t lo, uint32_t hi) {
    return __builtin_amdgcn_alignbit(hi, lo, 16);   // (lo.hi16, hi.lo16)
}
#else
static __device__ inline uint32_t mkp(uint32_t lo, uint32_t hi) {
    return (lo >> 16) | (hi << 16);
}
#endif

static __device__ inline uint32_t ldu(const u16* p) { return *(const uint32_t*)p; }

// ---------------------------------------------------------------------------
// Prepass: (b,c,h,w) fp32 -> (b,h,w,c) f16, LDS tile transpose per (b,h).
// ---------------------------------------------------------------------------
__global__ __launch_bounds__(256) void transpose_f16(
        const float* __restrict__ rgb, const float* __restrict__ dep,
        u16* __restrict__ rgbT, u16* __restrict__ depT) {
    const int bh = blockIdx.x;
    const float* src = blockIdx.y ? dep : rgb;
    u16* dst = blockIdx.y ? depT : rgbT;
    const int tid = threadIdx.x;
    const int b = bh >> 6, h = bh & 63;

    __shared__ u16 S[64 * 194];

    const float* srcb = src + (size_t)b * 786432 + (size_t)h * 192;
#pragma unroll
    for (int it = 0; it < 12; ++it) {
        const int idx = it * 256 + tid;      // 3072 = 64c x 48 float4
        const int c = idx / 48, w4 = idx - c * 48;
        const float4 v = *(const float4*)(srcb + (size_t)c * 12288 + 4 * w4);
        u16* sp = &S[c * 194 + 4 * w4];
        sp[0] = f2h(v.x); sp[1] = f2h(v.y); sp[2] = f2h(v.z); sp[3] = f2h(v.w);
    }
    __syncthreads();
    u16* dstb = dst + (size_t)bh * 192 * 64;
#pragma unroll
    for (int it = 0; it < 12; ++it) {
        const int idx = it * 256 + tid;      // 3072 = 192w x 16 c4
        const int w = idx >> 4, c4 = idx & 15;
        ushort4 o;
        o.x = S[(4 * c4 + 0) * 194 + w];
        o.y = S[(4 * c4 + 1) * 194 + w];
        o.z = S[(4 * c4 + 2) * 194 + w];
        o.w = S[(4 * c4 + 3) * 194 + w];
        *(ushort4*)(dstb + (size_t)w * 64 + 4 * c4) = o;
    }
}

// ---------------------------------------------------------------------------
// corr v5. Flat grid 2560, XCD-band swizzle (R11). 256 threads, no barriers.
// Per di: 5 deduped B tile-pairs loaded up front (k=-1..3; u0=w0base+16k;
// t uses k=t-1..t+1), 18 MFMA, u16 scatter into per-di Dall bank D4[i]
// (f2h at scatter). One merged readout at the end (no WAR drains).
// ---------------------------------------------------------------------------
__global__ __launch_bounds__(256) void corr_mfma(
        const u16* __restrict__ rgbT, const u16* __restrict__ depT,
        u16* __restrict__ out) {
    const int idx = blockIdx.x;
    const int band = idx & 7;
    const int j    = idx >> 3;
    const int dig  = j % 5;
    const int rest = j / 5;          // 0..63
    const int h    = band * 8 + (rest & 7);
    const int b    = rest >> 3;
    const int tid = threadIdx.x;
    const int lane = tid & 63, wave = tid >> 6;
    const int n = lane & 15, q = lane >> 4;
    const int w0base = wave * 48;

    __shared__ u16 D4[4][4080];      // per-di bank; addr = w*21 + (w>>2) + dj

    const u16* Abase = rgbT + (size_t)(b * 64 + h) * 12288;
    half8_t a0[3], a1[3];
#pragma unroll
    for (int t = 0; t < 3; ++t) {
        const half8_t* Ap = (const half8_t*)(Abase + (size_t)(w0base + t * 16 + n) * 64 + q * 8);
        a0[t] = Ap[0];               // c = q*8 .. q*8+7
        a1[t] = Ap[4];               // c += 32
    }

#pragma unroll
    for (int i = 0; i < 4; ++i) {
        const int di = dig * 4 + i;
        const int hd = h + di - 10;
        if (hd < 0 || hd >= 64) continue;    // block-uniform; zeros at readout

        const u16* Bbase = depT + (size_t)(b * 64 + hd) * 12288;
        // ---- load all 5 deduped B tile-pairs up front (MLP 10) ----
        half8_t B0[5], B1[5];
#pragma unroll
        for (int k = 0; k < 5; ++k) {
            const int u0 = w0base + (k - 1) * 16;
            if (u0 >= 0 && u0 <= 176) {      // wave-uniform
                const half8_t* Bp = (const half8_t*)(Bbase + (size_t)(u0 + n) * 64 + q * 8);
                B0[k] = Bp[0];
                B1[k] = Bp[4];
            } else {
                B0[k] = (half8_t)(f16_t)0.f;
                B1[k] = (half8_t)(f16_t)0.f;
            }
        }
#pragma unroll
        for (int t = 0; t < 3; ++t) {
            const int w0 = w0base + t * 16;
            f32x4 acc[3];
#pragma unroll
            for (int ut = 0; ut < 3; ++ut) {
                acc[ut].x = 0.f; acc[ut].y = 0.f; acc[ut].z = 0.f; acc[ut].w = 0.f;
            }
#pragma unroll
            for (int ut = 0; ut < 3; ++ut) {
                const int k = t + ut;        // array index for u-tile t+ut-1
                acc[ut] = __builtin_amdgcn_mfma_f32_16x16x32_f16(a0[t], B0[k], acc[ut], 0, 0, 0);
                acc[ut] = __builtin_amdgcn_mfma_f32_16x16x32_f16(a1[t], B1[k], acc[ut], 0, 0, 0);
            }
            // u16 scatter into this di's private bank (no WAR with other di)
#pragma unroll
            for (int ut = 0; ut < 3; ++ut) {
#pragma unroll
                for (int r = 0; r < 4; ++r) {
                    const int dj = 16 * ut + n - 4 * q - r - 6;
                    const int w = w0 + 4 * q + r;
                    if (dj >= 0 && dj < 20)
                        D4[i][w * 21 + (w >> 2) + dj] = f2h(acc[ut][r]);
                }
            }
        }
    }

    // ---- merged readout: one lgkm drain, then high-MLP reads + stores ----
#pragma unroll
    for (int i = 0; i < 4; ++i) {
        const int di = dig * 4 + i;
        const int hd = h + di - 10;
        const bool valid = (hd >= 0) && (hd < 64);   // block-uniform
        u16* outb = out + ((size_t)((b * 20 + di) * 20) * 64 + h) * 192;
#pragma unroll
        for (int it = 0; it < 4; ++it) {
            const int item = it * 64 + lane;
            if (item < 240) {
                const int dj = item / 12;
                const int w4 = wave * 12 + (item - dj * 12);
                ushort4 o;
                if (valid) {
                    const int base = 85 * w4 + dj;   // (4*w4+j)*21 + w4 + dj
                    o.x = D4[i][base];
                    o.y = D4[i][base + 21];
                    o.z = D4[i][base + 42];
                    o.w = D4[i][base + 63];
                } else {
                    o = make_ushort4(0, 0, 0, 0);
                }
                *(ushort4*)(outb + (size_t)dj * 12288 + 4 * w4) = o;
            }
        }
    }
}

// ---------------------------------------------------------------------------
// Fused block v9 (device body) — unchanged from R11.
// ---------------------------------------------------------------------------
template<int CIN, int COUT, int S, int DT, int DIN, int HIN, int WIN,
         int DO, int HO, int WO, typename TOUT>
static __device__ __forceinline__ void fused_impl(
        const u16* __restrict__ x,
        const float* __restrict__ dw_w, const float* __restrict__ dw_b,
        const float* __restrict__ pw_w, const float* __restrict__ pw_b,
        TOUT* __restrict__ y) {
    static_assert(WO % 48 == 0 && HO % 4 == 0, "tile divisibility");
    constexpr int CINP = (CIN == 20) ? 22 : 42;    // odd dword stride
    constexpr int NTASK = CIN * 12;
    constexpr int WT = WO / 48;
    constexpr int NP = S * (DT - 1) + 3;
    constexpr int ROWS = 3 * S + 3;                // 6 or 9
    constexpr int NL = (S == 1) ? 4 : 5;           // dwords per row
    constexpr int G  = (S == 1) ? 6 : 3;           // rows per load batch
    constexpr int NG = ROWS / G;

    const int wt = blockIdx.x % WT;
    const int ht = blockIdx.x / WT;
    const int d0 = blockIdx.y * DT;
    const int b  = blockIdx.z;
    const int tid = threadIdx.x;
    const int h0 = ht * 4;
    const int wbase = wt * 48;

    __shared__ float sDW[CIN * 27];
    __shared__ float sDB[CIN];
    __shared__ u16   sT[DT * 4 * 48 * CINP + 16];

    for (int i = tid; i < CIN * 27; i += 256) sDW[i] = dw_w[i];
    for (int i = tid; i < CIN; i += 256) sDB[i] = dw_b[i];
    __syncthreads();

    // ---------------- phase 1: depthwise via fdot2 ----------------
    for (int idx = tid; idx < NTASK; idx += 256) {
        const int ci = idx / 12;
        const int wg = idx - ci * 12;
        const int w0g = wbase + wg * 4;
        const int offA = (w0g > 0) ? -2 : 0;   // keeps corner load in-bounds

        half2_t KA[9], KB[9];
#pragma unroll
        for (int t = 0; t < 9; ++t) {
            const int kd = t / 3, kh = t - 3 * kd;
            const float k0 = sDW[ci * 27 + kd * 9 + kh * 3 + 0];
            const float k1 = sDW[ci * 27 + kd * 9 + kh * 3 + 1];
            const float k2 = sDW[ci * 27 + kd * 9 + kh * 3 + 2];
            half2_t a; a.x = (f16_t)k0; a.y = (f16_t)k1; KA[t] = a;
            half2_t bb;
            if constexpr (S == 1) { bb.x = (f16_t)k2; bb.y = (f16_t)0.f; }
            else                  { bb.x = (f16_t)0.f; bb.y = (f16_t)k2; }
            KB[t] = bb;
        }

        float acc[DT][4][4];
#pragma unroll
        for (int dl = 0; dl < DT; ++dl)
#pragma unroll
            for (int a = 0; a < 4; ++a)
#pragma unroll
                for (int c = 0; c < 4; ++c) acc[dl][a][c] = 0.f;

        const u16* plane0 = x + (size_t)(b * CIN + ci) * DIN * HIN * WIN;
#pragma unroll
        for (int p = 0; p < NP; ++p) {
            const int din = S * d0 - 1 + p;
            if (din < 0 || din >= DIN) continue;       // block-uniform, rare
            const u16* pl = plane0 + (size_t)din * HIN * WIN;
#pragma unroll
            for (int g = 0; g < NG; ++g) {
                // ---- load pass: all rows of this batch, unconditional ----
                uint32_t R[G][NL];
#pragma unroll
                for (int rr = 0; rr < G; ++rr) {
                    const int r = g * G + rr;
                    int hin = h0 * S - 1 + r;
                    int hc = hin < 0 ? 0 : (hin >= HIN ? HIN - 1 : hin);
                    const u16* rowp = pl + (size_t)hc * WIN + (size_t)w0g * S;
                    R[rr][0] = ldu(rowp + offA);
                    R[rr][1] = ldu(rowp);
                    R[rr][2] = ldu(rowp + 2);
                    R[rr][3] = ldu(rowp + 4);
                    if constexpr (S == 2) R[rr][4] = ldu(rowp + 6);
                }
                // ---- compute pass: masks + fdot2 ----
#pragma unroll
                for (int rr = 0; rr < G; ++rr) {
                    const int r = g * G + rr;
                    const int hin = h0 * S - 1 + r;
                    uint32_t D0 = R[rr][0], D1 = R[rr][1];
                    uint32_t D2 = R[rr][2], D3 = R[rr][3];
                    uint32_t E4 = 0;
                    if constexpr (S == 2) E4 = R[rr][4];
                    // w-edge masks (per-thread)
                    D0 = (w0g > 0) ? D0 : 0u;
                    if constexpr (S == 1) D3 = (w0g + 4 < WIN) ? D3 : 0u;
                    // h-validity: only boundary rows can be OOB.
                    if constexpr (S == 1) {
                        if (r == 0 || r == ROWS - 1) {
                            const bool rv = (hin >= 0) && (hin < HIN);
                            if (!rv) { D0 = 0; D1 = 0; D2 = 0; D3 = 0; }
                        }
                    } else {
                        if (r == 0) {
                            const bool rv = (hin >= 0);
                            if (!rv) { D0 = 0; D1 = 0; D2 = 0; D3 = 0; E4 = 0; }
                        }
                    }
                    uint32_t PA[4], PB[4];
                    if constexpr (S == 1) {
                        const uint32_t m01 = mkp(D0, D1);  // (x-1,x0)
                        const uint32_t m12 = mkp(D1, D2);  // (x1,x2)
                        const uint32_t m23 = mkp(D2, D3);  // (x3,x4)
                        PA[0] = m01; PA[1] = D1; PA[2] = m12; PA[3] = D2;
                        PB[0] = m12; PB[1] = D2; PB[2] = m23; PB[3] = D3;
                    } else {
                        PA[0] = mkp(D0, D1); PA[1] = mkp(D1, D2);
                        PA[2] = mkp(D2, D3); PA[3] = mkp(D3, E4);
                        PB[0] = D1; PB[1] = D2; PB[2] = D3; PB[3] = E4;
                    }
#pragma unroll
                    for (int dl = 0; dl < DT; ++dl) {
                        const int kd = p - S * dl;         // folds after unroll
                        if (kd < 0 || kd > 2) continue;
#pragma unroll
                        for (int hh = 0; hh < 4; ++hh) {
                            const int kh = r - S * hh;     // folds after unroll
                            if (kh < 0 || kh > 2) continue;
                            const int t = kd * 3 + kh;
#pragma unroll
                            for (int k = 0; k < 4; ++k)
                                acc[dl][hh][k] = FDOT2(H2(PB[k]), KB[t],
                                                 FDOT2(H2(PA[k]), KA[t],
                                                       acc[dl][hh][k]));
                        }
                    }
                }
            }
        }

        const float bia = sDB[ci];
#pragma unroll
        for (int dl = 0; dl < DT; ++dl) {
#pragma unroll
            for (int hh = 0; hh < 4; ++hh) {
#pragma unroll
                for (int k = 0; k < 4; ++k) {
                    const float t = acc[dl][hh][k] + bia;
                    sT[((dl * 4 + hh) * 48 + wg * 4 + k) * CINP + ci] =
                        f2h(fmaxf(t, 0.1f * t));
                }
            }
        }
    }
    __syncthreads();

    // ---------------- phase 2: pointwise via f16 MFMA ----------------
    constexpr int NT = (COUT + 15) / 16;   // co tiles
    constexpr int KH = (CIN + 31) / 32;    // K=32 chunks
    constexpr int MTW = DT * 3;            // M-tiles per wave
    const int lane = tid & 63, wave = tid >> 6;
    const int m15 = lane & 15, q = lane >> 4;

    half8_t bf[NT][KH];
    float   pb[NT];
#pragma unroll
    for (int nt = 0; nt < NT; ++nt) {
        const int co = nt * 16 + m15;
        pb[nt] = (co < COUT) ? pw_b[co] : 0.f;
#pragma unroll
        for (int kh = 0; kh < KH; ++kh) {
            union { half8_t v; f16_t e[8]; } u;
#pragma unroll
            for (int j = 0; j < 8; ++j) {
                const int ci = kh * 32 + q * 8 + j;
                u.e[j] = (co < COUT && ci < CIN)
                         ? (f16_t)pw_w[co * CIN + ci] : (f16_t)0.f;
            }
            bf[nt][kh] = u.v;
        }
    }

    const size_t planeSz = (size_t)DO * HO * WO;
    for (int mt = wave * MTW; mt < (wave + 1) * MTW; ++mt) {
        const int dl  = mt / 12;
        const int rem = mt - dl * 12;
        const int hh  = rem / 3;
        const int w0  = (rem - hh * 3) * 16;
        if (d0 + dl >= DO) continue;           // tail guard

        const int pos0 = (dl * 4 + hh) * 48 + w0 + m15;
        const u16* ap = &sT[(size_t)pos0 * CINP];
        union { uint32_t u[4]; half8_t v; } af[KH];
#pragma unroll
        for (int kh = 0; kh < KH; ++kh) {
            const int ci0 = kh * 32 + q * 8;
            af[kh].u[0] = (ci0     < CIN) ? ldu(ap + ci0)     : 0u;
            af[kh].u[1] = (ci0 + 2 < CIN) ? ldu(ap + ci0 + 2) : 0u;
            af[kh].u[2] = (ci0 + 4 < CIN) ? ldu(ap + ci0 + 4) : 0u;
            af[kh].u[3] = (ci0 + 6 < CIN) ? ldu(ap + ci0 + 6) : 0u;
        }
#pragma unroll
        for (int nt = 0; nt < NT; ++nt) {
            f32x4 acc;
            acc.x = 0.f; acc.y = 0.f; acc.z = 0.f; acc.w = 0.f;
#pragma unroll
            for (int kh = 0; kh < KH; ++kh)
                acc = __builtin_amdgcn_mfma_f32_16x16x32_f16(
                          af[kh].v, bf[nt][kh], acc, 0, 0, 0);
            const int co = nt * 16 + m15;
            if (co < COUT) {
                const float bias = pb[nt];
                TOUT* yp = y + (size_t)b * COUT * planeSz + (size_t)co * planeSz
                             + (size_t)(d0 + dl) * HO * WO
                             + (size_t)(h0 + hh) * WO + wbase + w0 + q * 4;
                float s0 = acc.x + bias, s1 = acc.y + bias;
                float s2 = acc.z + bias, s3 = acc.w + bias;
                s0 = fmaxf(s0, 0.1f * s0); s1 = fmaxf(s1, 0.1f * s1);
                s2 = fmaxf(s2, 0.1f * s2); s3 = fmaxf(s3, 0.1f * s3);
                if constexpr (sizeof(TOUT) == 4) {
                    float4 o; o.x = s0; o.y = s1; o.z = s2; o.w = s3;
                    *(float4*)yp = o;
                } else {
                    ushort4 o;
                    o.x = f2h(s0); o.y = f2h(s1); o.z = f2h(s2); o.w = f2h(s3);
                    *(ushort4*)yp = o;
                }
            }
        }
    }
}

// Named wrappers -> per-stage visibility in rocprof.
__global__ __launch_bounds__(256) void fb1_dwpw(
        const u16* __restrict__ x, const float* __restrict__ dww,
        const float* __restrict__ dwb, const float* __restrict__ pww,
        const float* __restrict__ pwb, u16* __restrict__ y) {
    fused_impl<20, 20, 1, 2, 20, 64, 192, 20, 64, 192, u16>(x, dww, dwb, pww, pwb, y);
}
__global__ __launch_bounds__(256) void fb2_dwpw(
        const u16* __restrict__ x, const float* __restrict__ dww,
        const float* __restrict__ dwb, const float* __restrict__ pww,
        const float* __restrict__ pwb, u16* __restrict__ y) {
    fused_impl<20, 40, 2, 2, 20, 64, 192, 10, 32, 96, u16>(x, dww, dwb, pww, pwb, y);
}
__global__ __launch_bounds__(256) void fb3_dwpw(
        const u16* __restrict__ x, const float* __restrict__ dww,
        const float* __restrict__ dwb, const float* __restrict__ pww,
        const float* __restrict__ pwb, u16* __restrict__ y) {
    fused_impl<40, 40, 1, 1, 10, 32, 96, 10, 32, 96, u16>(x, dww, dwb, pww, pwb, y);
}
__global__ __launch_bounds__(256) void fb4_dwpw(
        const u16* __restrict__ x, const float* __restrict__ dww,
        const float* __restrict__ dwb, const float* __restrict__ pww,
        const float* __restrict__ pwb, float* __restrict__ y) {
    fused_impl<40, 80, 2, 1, 10, 32, 96, 5, 16, 48, float>(x, dww, dwb, pww, pwb, y);
}

// ---------------------------------------------------------------------------
extern "C" void kernel_launch(void* const* d_in, const int* in_sizes, int n_in,
                              void* d_out, int out_size, void* d_ws, size_t ws_size,
                              hipStream_t stream) {
    const float* rgb  = (const float*)d_in[0];
    const float* dep  = (const float*)d_in[1];
    const float* dw1w = (const float*)d_in[2];
    const float* dw1b = (const float*)d_in[3];
    const float* pw1w = (const float*)d_in[4];
    const float* pw1b = (const float*)d_in[5];
    const float* dw2w = (const float*)d_in[6];
    const float* dw2b = (const float*)d_in[7];
    const float* pw2w = (const float*)d_in[8];
    const float* pw2b = (const float*)d_in[9];
    const float* dw3w = (const float*)d_in[10];
    const float* dw3b = (const float*)d_in[11];
    const float* pw3w = (const float*)d_in[12];
    const float* pw3b = (const float*)d_in[13];
    const float* dw4w = (const float*)d_in[14];
    const float* dw4b = (const float*)d_in[15];
    const float* pw4w = (const float*)d_in[16];
    const float* pw4b = (const float*)d_in[17];

    const size_t HALF = 78643200;
    u16* corrO = (u16*)d_ws;
    u16* rgbT  = (u16*)((char*)d_ws + HALF);
    u16* depT  = (u16*)((char*)d_ws + HALF + 12582912);
    u16* b1o   = (u16*)((char*)d_ws + HALF);   // rgbT/depT dead by then
    u16* b2o   = (u16*)d_ws;                   // corrO dead by then
    u16* b3o   = (u16*)((char*)d_ws + HALF);   // b1o dead by then
    float* outp = (float*)d_out;

    transpose_f16<<<dim3(512, 2), 256, 0, stream>>>(rgb, dep, rgbT, depT);

    corr_mfma<<<dim3(2560), 256, 0, stream>>>(rgbT, depT, corrO);

    fb1_dwpw<<<dim3(64, 10, 8), 256, 0, stream>>>(corrO, dw1w, dw1b, pw1w, pw1b, b1o);
    fb2_dwpw<<<dim3(16, 5, 8), 256, 0, stream>>>(b1o, dw2w, dw2b, pw2w, pw2b, b2o);
    fb3_dwpw<<<dim3(16, 10, 8), 256, 0, stream>>>(b2o, dw3w, dw3b, pw3w, pw3b, b3o);
    fb4_dwpw<<<dim3(4, 5, 8), 256, 0, stream>>>(b3o, dw4w, dw4b, pw4w, pw4b, outp);
}